// Round 10
// baseline (3251.399 us; speedup 1.0000x reference)
//
#include <hip/hip_runtime.h>
#include <hip/hip_bf16.h>

typedef __hip_bfloat16 bf16;
typedef __attribute__((ext_vector_type(8))) short bf16x8;   // MFMA A/B frag (8 bf16)
typedef __attribute__((ext_vector_type(4))) short bf16x4;
typedef __attribute__((ext_vector_type(4))) float f32x4;    // MFMA C/D frag

__device__ __forceinline__ void stC(float* p, float v) { *p = v; }
__device__ __forceinline__ void stC(bf16* p, float v)  { *p = __float2bfloat16(v); }

__device__ __forceinline__ short f2s(float f) {
    bf16 b = __float2bfloat16(f);
    return __builtin_bit_cast(short, b);
}

// global -> LDS direct copy, 16B per lane (lds dest = wave-uniform base + lane*16)
__device__ __forceinline__ void gload16(const void* gp, void* lp) {
    __builtin_amdgcn_global_load_lds(
        (const __attribute__((address_space(1))) void*)gp,
        (__attribute__((address_space(3))) void*)lp, 16, 0, 0);
}

// NaN-proof activations (clamp = no-op on sane data, sanitizes garbage).
__device__ __forceinline__ float sigm(float x) {
    x = fminf(fmaxf(x, -40.f), 40.f);
    return 1.f / (1.f + expf(-x));
}
__device__ __forceinline__ float tanh_s(float x) {
    x = fminf(fmaxf(x, -20.f), 20.f);
    float e = expf(2.f * x);
    return 1.f - 2.f / (e + 1.f);
}

// 16B-aligned 8-element loads -> bf16x8
__device__ __forceinline__ bf16x8 ld8(const bf16* p) {
    return *reinterpret_cast<const bf16x8*>(p);
}
__device__ __forceinline__ bf16x8 ld8(const float* p) {
    const float4 f0 = *reinterpret_cast<const float4*>(p);
    const float4 f1 = *reinterpret_cast<const float4*>(p + 4);
    bf16x8 v;
    v[0] = f2s(f0.x); v[1] = f2s(f0.y); v[2] = f2s(f0.z); v[3] = f2s(f0.w);
    v[4] = f2s(f1.x); v[5] = f2s(f1.y); v[6] = f2s(f1.z); v[7] = f2s(f1.w);
    return v;
}
// 8B-aligned 8-element load (rows with odd*8B stride)
__device__ __forceinline__ bf16x8 ld8_8B(const bf16* p) {
    bf16x4 lo = *reinterpret_cast<const bf16x4*>(p);
    bf16x4 hi = *reinterpret_cast<const bf16x4*>(p + 4);
    bf16x8 v;
    v[0] = lo[0]; v[1] = lo[1]; v[2] = lo[2]; v[3] = lo[3];
    v[4] = hi[0]; v[5] = hi[1]; v[6] = hi[2]; v[7] = hi[3];
    return v;
}

// f32 -> bf16 bulk convert
__global__ void f2b(const float* __restrict__ src, bf16* __restrict__ dst, long n) {
    long i = (long)blockIdx.x * 256 + threadIdx.x;
    if (i < n) dst[i] = __float2bfloat16(src[i]);
}
// f32 [rows,Ks] -> bf16 [rows,Kd] with zero pad cols
__global__ void f2bpad(const float* __restrict__ src, bf16* __restrict__ dst,
                       int rows, int Ks, int Kd) {
    long i = (long)blockIdx.x * 256 + threadIdx.x;
    if (i >= (long)rows * Kd) return;
    int c = i % Kd; long r = i / Kd;
    dst[i] = __float2bfloat16(c < Ks ? src[r * Ks + c] : 0.f);
}
// word Wih1 remap: f32 [rows,150] -> bf16 [rows,160]; col c<75 -> c;
// 80<=c<155 -> c-5; else 0 (matches y0w padded layout d*80+j).
__global__ void f2bremap(const float* __restrict__ src, bf16* __restrict__ dst, int rows) {
    long i = (long)blockIdx.x * 256 + threadIdx.x;
    if (i >= (long)rows * 160) return;
    int c = i % 160; long r = i / 160;
    float v = 0.f;
    if (c < 75) v = src[r * 150 + c];
    else if (c >= 80 && c < 155) v = src[r * 150 + c - 5];
    dst[i] = __float2bfloat16(v);
}

// ==================== MFMA GEMM (f32 inputs, embW only) ====================
#define MBM 128
#define MBN 64
#define MLD 40

__global__ __launch_bounds__(256) void gemm_mfma(
    const float* __restrict__ A, long sAd,
    const float* __restrict__ W, long sWd,
    bf16* __restrict__ C, long sCd,
    int M, int Nc, int K)   // K % 8 == 0
{
    __shared__ bf16 As[MBM * MLD];
    __shared__ bf16 Ws[MBN * MLD];
    const int d = blockIdx.z;
    A += (long)d * sAd; W += (long)d * sWd; C += (long)d * sCd;
    const int m0 = blockIdx.y * MBM;
    const int n0 = blockIdx.x * MBN;
    const int tid = threadIdx.x;
    const int w = tid >> 6, l = tid & 63;
    const int lr = l & 15, lq = l >> 4;

    f32x4 acc[2][4] = {};
    for (int k0 = 0; k0 < K; k0 += 32) {
#pragma unroll
        for (int i = 0; i < 2; ++i) {
            int u = tid + i * 256;
            int r = u >> 2, kk = (u & 3) * 8;
            bf16x8 v = {};
            if (m0 + r < M && k0 + kk < K)
                v = ld8(A + (long)(m0 + r) * K + k0 + kk);
            *reinterpret_cast<bf16x8*>(&As[r * MLD + kk]) = v;
        }
        {
            int r = tid >> 2, kk = (tid & 3) * 8;
            bf16x8 v = {};
            if (n0 + r < Nc && k0 + kk < K)
                v = ld8(W + (long)(n0 + r) * K + k0 + kk);
            *reinterpret_cast<bf16x8*>(&Ws[r * MLD + kk]) = v;
        }
        __syncthreads();
        bf16x8 af[2], bw[4];
        af[0] = *reinterpret_cast<const bf16x8*>(&As[(w * 32 + lr) * MLD + lq * 8]);
        af[1] = *reinterpret_cast<const bf16x8*>(&As[(w * 32 + 16 + lr) * MLD + lq * 8]);
#pragma unroll
        for (int ni = 0; ni < 4; ++ni)
            bw[ni] = *reinterpret_cast<const bf16x8*>(&Ws[(ni * 16 + lr) * MLD + lq * 8]);
#pragma unroll
        for (int mi = 0; mi < 2; ++mi)
#pragma unroll
            for (int ni = 0; ni < 4; ++ni)
                acc[mi][ni] = __builtin_amdgcn_mfma_f32_16x16x32_bf16(
                    af[mi], bw[ni], acc[mi][ni], 0, 0, 0);
        __syncthreads();
    }
#pragma unroll
    for (int mi = 0; mi < 2; ++mi)
#pragma unroll
        for (int reg = 0; reg < 4; ++reg) {
            int m = m0 + w * 32 + mi * 16 + lq * 4 + reg;
            if (m >= M) continue;
#pragma unroll
            for (int ni = 0; ni < 4; ++ni) {
                int n = n0 + ni * 16 + lr;
                if (n < Nc) stC(&C[(long)m * Nc + n], acc[mi][ni][reg]);
            }
        }
}

// ==== all-bf16 GEMM: 128x128 tile, BK=64, global_load_lds, XOR swizzle ====
// C[d] = A[d] (MxKP bf16, M%128==0, KP%64==0) @ W[d]^T
// (W: [NcPad x KP] bf16, NcPad 128-aligned, pad cols zero; pad-row garbage
// only feeds discarded output cols). Staging via global_load_lds width=16:
// linear LDS dest (wave base + lane*16), per-lane PRE-SWIZZLED global source
// (granule sg = g ^ (r&7)); read side applies the same XOR -> conflict-free
// (verified round 9: SQ_LDS_BANK_CONFLICT = 0). m97 2-barrier loop; latency
// hidden by multi-block TLP (32 KB LDS -> up to 5 blocks/CU).
// Band-of-8 x-tile swizzle for A-panel L2 reuse.
__global__ __launch_bounds__(256) void gemm_bt(
    const bf16* __restrict__ A, long sAd,
    const bf16* __restrict__ W, long sWd,
    bf16* __restrict__ C, long sCd,
    int M, int Nc, int KP)
{
    __shared__ bf16 As[128 * 64];
    __shared__ bf16 Ws[128 * 64];
    const int d = blockIdx.z;
    A += (long)d * sAd; W += (long)d * sWd; C += (long)d * sCd;
    const int nx = (Nc + 127) >> 7, ny = M >> 7;
    int id = blockIdx.x;
    int band = id / (8 * ny);
    int rr = id - band * 8 * ny;
    int bwd = nx - band * 8; if (bwd > 8) bwd = 8;
    const int bx = band * 8 + rr % bwd;
    const int by = rr / bwd;
    const int m0 = by << 7;
    const int n0 = bx << 7;
    const int tid = threadIdx.x;
    const int w = tid >> 6, l = tid & 63;
    const int lr = l & 15, lq = l >> 4;

    // per-lane staging coords: issue j covers LDS granules G = (w*4+j)*64 + l;
    // r = G>>3, g = G&7; global col granule = g ^ (r&7)  (inverse swizzle)
    int rof[4], cof[4];
#pragma unroll
    for (int j = 0; j < 4; ++j) {
        int G = (w * 4 + j) * 64 + l;
        int r = G >> 3, g = G & 7;
        rof[j] = r;
        cof[j] = (g ^ (r & 7)) * 8;
    }

    f32x4 acc[2][8] = {};
    for (int k0 = 0; k0 < KP; k0 += 64) {
#pragma unroll
        for (int j = 0; j < 4; ++j)
            gload16(A + (long)(m0 + rof[j]) * KP + k0 + cof[j],
                    &As[(w * 4 + j) * 512]);
#pragma unroll
        for (int j = 0; j < 4; ++j)
            gload16(W + (long)(n0 + rof[j]) * KP + k0 + cof[j],
                    &Ws[(w * 4 + j) * 512]);
        __syncthreads();   // drains vmcnt: LDS ready
#pragma unroll
        for (int ks = 0; ks < 2; ++ks) {
            const int gb = ks * 4 + lq;
            bf16x8 af[2], bw8[8];
#pragma unroll
            for (int mi = 0; mi < 2; ++mi) {
                const int r = w * 32 + mi * 16 + lr;
                af[mi] = *reinterpret_cast<const bf16x8*>(
                    &As[r * 64 + (gb ^ (r & 7)) * 8]);
            }
#pragma unroll
            for (int ni = 0; ni < 8; ++ni) {
                const int r = ni * 16 + lr;
                bw8[ni] = *reinterpret_cast<const bf16x8*>(
                    &Ws[r * 64 + (gb ^ (r & 7)) * 8]);
            }
#pragma unroll
            for (int mi = 0; mi < 2; ++mi)
#pragma unroll
                for (int ni = 0; ni < 8; ++ni)
                    acc[mi][ni] = __builtin_amdgcn_mfma_f32_16x16x32_bf16(
                        af[mi], bw8[ni], acc[mi][ni], 0, 0, 0);
        }
        __syncthreads();   // reads done before next overwrite
    }
#pragma unroll
    for (int mi = 0; mi < 2; ++mi)
#pragma unroll
        for (int reg = 0; reg < 4; ++reg) {
            int m = m0 + w * 32 + mi * 16 + lq * 4 + reg;
#pragma unroll
            for (int ni = 0; ni < 8; ++ni) {
                int n = n0 + ni * 16 + lr;
                if (n < Nc) C[(long)m * Nc + n] = __float2bfloat16(acc[mi][ni][reg]);
            }
        }
}

// ========== fused dual-job sentence GRU step (MFMA, LDS-staged) ==========
#define NKS 22                  // ceil(700/32)
#define HBPE (2 * 128 * 700)    // h_bf ping stride in elems

struct StepJob {
    const bf16* Whh;   // [2,2100,700] bf16
    const bf16* xw;    // [2,Cbuf,128,2100] bf16 (chunk-local)
    const float* bih;  // [2,2100]
    const float* bhh;
    float* h;          // [2,128,700] f32 master
    const bf16* hr;    // read ping
    bf16* hw;          // write pong
    bf16* y;           // [L,128,1408] or nullptr
    const bf16* zb;    // 256B zero scratch (pad-row source for gload16)
    int te0, te1;      // t_eff for d=0 / d=1 (y writes)
    int tl0, tl1;      // chunk-local t (xw reads)
};

__global__ __launch_bounds__(512) void gru_step_sent2(StepJob ja, StepJob jb, int Cbuf)
{
    extern __shared__ bf16 Wlds[];  // 66 issues x 1KB = 67,584 B
    const StepJob J = blockIdx.y ? jb : ja;
    const int jt = blockIdx.x, d = blockIdx.z;
    const int tid = threadIdx.x;
    const int w = tid >> 6, l = tid & 63;
    const int lr = l & 15, lq = l >> 4;
    const int j0c = jt * 16;
    const int jcol = j0c + lr;
    const bool jok = jcol < 700;

    // ---- Whh -> LDS via global_load_lds (issued FIRST: deepest latency).
    // unit u = issue*64 + l; issue = kk*3 + g; row = j0c + (l&15),
    // k = kk*32 + (l>>4)*8. Pad rows (>=700) read the zero scratch; the
    // k=696 granule's 4-elem overrun multiplies A's zeroed tail -> exact 0.
    const bf16* Wd = J.Whh + (long)d * 2100 * 700;
    {
        const int row = j0c + lr;
        const int kof = lq * 8;
#pragma unroll
        for (int i = 0; i < 9; ++i) {
            const int issue = w + i * 8;        // wave-uniform
            if (issue < 66) {
                const int g = issue % 3;
                const int kk = issue / 3;
                const bf16* src = (row < 700)
                    ? Wd + (long)(g * 700 + row) * 700 + kk * 32 + kof
                    : J.zb;
                gload16(src, &Wlds[(long)issue * 512]);
            }
        }
    }

    // ---- A-frags (L2-resident h state) ----
    const int arow = w * 16 + lr;
    const bf16* Ab = J.hr + ((long)d * 128 + arow) * 700;
    bf16x8 areg[NKS];
#pragma unroll
    for (int kk = 0; kk < NKS; ++kk) {
        const int kb = kk * 32 + lq * 8;
        if (kb + 8 <= 700) {
            areg[kk] = ld8_8B(Ab + kb);
        } else {
            bf16x8 v = {};
            bf16x4 lo = *reinterpret_cast<const bf16x4*>(Ab + kb);
            v[0] = lo[0]; v[1] = lo[1]; v[2] = lo[2]; v[3] = lo[3];
            areg[kk] = v;
        }
    }

    // ---- xw gates + biases (h-independent) ----
    const int te = d ? J.te1 : J.te0;
    const int tl = d ? J.tl1 : J.tl0;
    const bf16* xbase = J.xw + ((long)d * Cbuf + tl) * 128 * 2100;
    bf16 xg[3][4];
#pragma unroll
    for (int reg = 0; reg < 4; ++reg) {
        const int m = w * 16 + lq * 4 + reg;
        const bf16* xp = xbase + (long)m * 2100 + jcol;
#pragma unroll
        for (int g = 0; g < 3; ++g) xg[g][reg] = jok ? xp[g * 700] : bf16(0.f);
    }
    const int jc = jok ? jcol : 699;
    const float bir = J.bih[d * 2100 + jc];
    const float biz = J.bih[d * 2100 + 700 + jc];
    const float bin = J.bih[d * 2100 + 1400 + jc];
    const float bhr = J.bhh[d * 2100 + jc];
    const float bhz = J.bhh[d * 2100 + 700 + jc];
    const float bhn = J.bhh[d * 2100 + 1400 + jc];

    __syncthreads();   // drains vmcnt: Wlds + areg ready

    f32x4 acc[3] = {};
#pragma unroll
    for (int kk = 0; kk < NKS; ++kk)
#pragma unroll
        for (int g = 0; g < 3; ++g) {
            bf16x8 b = *reinterpret_cast<const bf16x8*>(&Wlds[((kk * 3 + g) * 64 + l) * 8]);
            acc[g] = __builtin_amdgcn_mfma_f32_16x16x32_bf16(areg[kk], b, acc[g], 0, 0, 0);
        }

    if (jok) {
#pragma unroll
        for (int reg = 0; reg < 4; ++reg) {
            const int m = w * 16 + lq * 4 + reg;
            float r  = sigm((float)xg[0][reg] + bir + acc[0][reg] + bhr);
            float z  = sigm((float)xg[1][reg] + biz + acc[1][reg] + bhz);
            float nn = tanh_s((float)xg[2][reg] + bin + r * (acc[2][reg] + bhn));
            const long hidx = ((long)d * 128 + m) * 700 + jcol;
            const float hnew = (1.f - z) * nn + z * J.h[hidx];
            J.h[hidx] = hnew;
            J.hw[hidx] = __float2bfloat16(hnew);
            if (J.y) J.y[((long)te * 128 + m) * 1408 + (long)d * 700 + jcol] =
                         __float2bfloat16(hnew);
        }
    }
}

// ============ fused word GRU steps (same structure, H=75) ============
#define WNW 15360

// layer 0: x-gates gathered from embW[tok]; gh via MFMA (3 ksteps).
__global__ __launch_bounds__(512) void gru_word0_fused(
    const int* __restrict__ x,       // [S,T,B]
    const bf16* __restrict__ embW,   // [2,30000,225]
    const bf16* __restrict__ Whh,    // [2,225,80] zero-padded
    const float* __restrict__ bih,   // [2,225]
    const float* __restrict__ bhh,
    const bf16* __restrict__ hr,     // ping [2,Nw,96]
    bf16* __restrict__ hw,           // pong
    float* __restrict__ h,           // [2,Nw,75] f32
    bf16* __restrict__ y,            // [T,Nw,160]
    int T, int k)
{
    __shared__ bf16 Wl[3 * 3 * 64 * 8];
    const int jt = blockIdx.x, mt = blockIdx.y, d = blockIdx.z;
    const int tid = threadIdx.x;
    const int w = tid >> 6, l = tid & 63;
    const int lr = l & 15, lq = l >> 4;
    const int j0c = jt * 16, jcol = j0c + lr;
    const bool jok = jcol < 75;
    const int t_eff = d ? (T - 1 - k) : k;

    const int na = mt * 128 + w * 16 + lr;
    const bf16* Ab = hr + ((long)d * WNW + na) * 96;
    bf16x8 areg[3];
#pragma unroll
    for (int kk = 0; kk < 3; ++kk) areg[kk] = ld8(Ab + kk * 32 + lq * 8);

    float xg[3][4];
#pragma unroll
    for (int reg = 0; reg < 4; ++reg) {
        const int m = mt * 128 + w * 16 + lq * 4 + reg;
        const int s = m >> 7, b = m & 127;
        int tok = x[(s * T + t_eff) * 128 + b];
        tok = max(0, min(29999, tok));
        const bf16* ep = embW + ((long)d * 30000 + tok) * 225;
#pragma unroll
        for (int g = 0; g < 3; ++g)
            xg[g][reg] = jok ? (float)ep[g * 75 + jcol] : 0.f;
    }
    const int jc = jok ? jcol : 74;
    const float bir = bih[d*225+jc], biz = bih[d*225+75+jc], bin = bih[d*225+150+jc];
    const float bhr = bhh[d*225+jc], bhz = bhh[d*225+75+jc], bhn = bhh[d*225+150+jc];

    const bf16* Wd = Whh + (long)d * 225 * 80;
    for (int u = tid; u < 3 * 3 * 64; u += 512) {
        int lane = u & 63;
        int g = (u >> 6) % 3;
        int kk = u / 192;
        int row = j0c + (lane & 15);
        int kb = kk * 32 + (lane >> 4) * 8;
        bf16x8 v = {};
        if (row < 75 && kb < 80) v = ld8_8B(Wd + (long)(g * 75 + row) * 80 + kb);
        *reinterpret_cast<bf16x8*>(&Wl[u * 8]) = v;
    }
    __syncthreads();

    f32x4 acc[3] = {};
#pragma unroll
    for (int kk = 0; kk < 3; ++kk)
#pragma unroll
        for (int g = 0; g < 3; ++g) {
            bf16x8 b8 = *reinterpret_cast<const bf16x8*>(&Wl[((kk*3+g)*64 + l)*8]);
            acc[g] = __builtin_amdgcn_mfma_f32_16x16x32_bf16(areg[kk], b8, acc[g], 0, 0, 0);
        }

    if (jok) {
#pragma unroll
        for (int reg = 0; reg < 4; ++reg) {
            const int m = mt * 128 + w * 16 + lq * 4 + reg;
            float r  = sigm(xg[0][reg] + bir + acc[0][reg] + bhr);
            float z  = sigm(xg[1][reg] + biz + acc[1][reg] + bhz);
            float nn = tanh_s(xg[2][reg] + bin + r * (acc[2][reg] + bhn));
            const long hif = ((long)d * WNW + m) * 75 + jcol;
            const float hnew = (1.f - z) * nn + z * h[hif];
            h[hif] = hnew;
            hw[((long)d * WNW + m) * 96 + jcol] = __float2bfloat16(hnew);
            y[((long)t_eff * WNW + m) * 160 + d * 80 + jcol] = __float2bfloat16(hnew);
        }
    }
}

// layer 1: xw (y0 @ Wih^T, 5 ksteps) AND gh (3 ksteps) fused via MFMA.
__global__ __launch_bounds__(512) void gru_word1_fused(
    const bf16* __restrict__ y0,     // [T,Nw,160]
    const bf16* __restrict__ Wih,    // [2,225,160] remapped
    const bf16* __restrict__ Whh,    // [2,225,80]
    const float* __restrict__ bih,
    const float* __restrict__ bhh,
    const bf16* __restrict__ hr,
    bf16* __restrict__ hw,
    float* __restrict__ h,           // [2,Nw,75]
    int T, int k)
{
    __shared__ bf16 Wl[8 * 3 * 64 * 8];   // 5 xw + 3 hh ksteps
    const int jt = blockIdx.x, mt = blockIdx.y, d = blockIdx.z;
    const int tid = threadIdx.x;
    const int w = tid >> 6, l = tid & 63;
    const int lr = l & 15, lq = l >> 4;
    const int j0c = jt * 16, jcol = j0c + lr;
    const bool jok = jcol < 75;
    const int t_eff = d ? (T - 1 - k) : k;

    const int na = mt * 128 + w * 16 + lr;
    const bf16* A1 = y0 + ((long)t_eff * WNW + na) * 160;
    bf16x8 a1[5];
#pragma unroll
    for (int kk = 0; kk < 5; ++kk) a1[kk] = ld8(A1 + kk * 32 + lq * 8);
    const bf16* A2 = hr + ((long)d * WNW + na) * 96;
    bf16x8 a2[3];
#pragma unroll
    for (int kk = 0; kk < 3; ++kk) a2[kk] = ld8(A2 + kk * 32 + lq * 8);

    const int jc = jok ? jcol : 74;
    const float bir = bih[d*225+jc], biz = bih[d*225+75+jc], bin = bih[d*225+150+jc];
    const float bhr = bhh[d*225+jc], bhz = bhh[d*225+75+jc], bhn = bhh[d*225+150+jc];

    const bf16* Wx = Wih + (long)d * 225 * 160;
    for (int u = tid; u < 960; u += 512) {       // 5*3*64 units
        int lane = u & 63;
        int g = (u >> 6) % 3;
        int kk = u / 192;
        int row = j0c + (lane & 15);
        int kb = kk * 32 + (lane >> 4) * 8;
        bf16x8 v = {};
        if (row < 75) v = ld8(Wx + (long)(g * 75 + row) * 160 + kb);
        *reinterpret_cast<bf16x8*>(&Wl[u * 8]) = v;
    }
    const bf16* Wd = Whh + (long)d * 225 * 80;
    for (int u = tid; u < 576; u += 512) {       // 3*3*64 units
        int lane = u & 63;
        int g = (u >> 6) % 3;
        int kk = u / 192;
        int row = j0c + (lane & 15);
        int kb = kk * 32 + (lane >> 4) * 8;
        bf16x8 v = {};
        if (row < 75 && kb < 80) v = ld8_8B(Wd + (long)(g * 75 + row) * 80 + kb);
        *reinterpret_cast<bf16x8*>(&Wl[(960 + u) * 8]) = v;
    }
    __syncthreads();

    f32x4 ax[3] = {}, ah[3] = {};
#pragma unroll
    for (int kk = 0; kk < 5; ++kk)
#pragma unroll
        for (int g = 0; g < 3; ++g) {
            bf16x8 b8 = *reinterpret_cast<const bf16x8*>(&Wl[((kk*3+g)*64 + l)*8]);
            ax[g] = __builtin_amdgcn_mfma_f32_16x16x32_bf16(a1[kk], b8, ax[g], 0, 0, 0);
        }
#pragma unroll
    for (int kk = 0; kk < 3; ++kk)
#pragma unroll
        for (int g = 0; g < 3; ++g) {
            bf16x8 b8 = *reinterpret_cast<const bf16x8*>(&Wl[(960 + (kk*3+g)*64 + l)*8]);
            ah[g] = __builtin_amdgcn_mfma_f32_16x16x32_bf16(a2[kk], b8, ah[g], 0, 0, 0);
        }

    if (jok) {
#pragma unroll
        for (int reg = 0; reg < 4; ++reg) {
            const int m = mt * 128 + w * 16 + lq * 4 + reg;
            float r  = sigm(ax[0][reg] + bir + ah[0][reg] + bhr);
            float z  = sigm(ax[1][reg] + biz + ah[1][reg] + bhz);
            float nn = tanh_s(ax[2][reg] + bin + r * (ah[2][reg] + bhn));
            const long hif = ((long)d * WNW + m) * 75 + jcol;
            const float hnew = (1.f - z) * nn + z * h[hif];
            h[hif] = hnew;
            hw[((long)d * WNW + m) * 96 + jcol] = __float2bfloat16(hnew);
        }
    }
}

// out[n*OS + c] = [ha_d0 | ha_d1 | hb_d0 | hb_d1], c in [0,4H)
template <typename OT>
__global__ void concat4(const float* __restrict__ ha, const float* __restrict__ hb,
                        OT* __restrict__ out, int N, int H, int OS)
{
    long idx = (long)blockIdx.x * 256 + threadIdx.x;
    int C4 = 4 * H;
    if (idx >= (long)N * C4) return;
    int c = idx % C4;
    long n = idx / C4;
    int blk = c / H, j = c % H;
    const float* src = (blk < 2) ? ha : hb;
    int dd = blk & 1;
    stC(&out[n * (long)OS + c], src[((long)dd * N + n) * H + j]);
}

extern "C" void kernel_launch(void* const* d_in, const int* in_sizes, int n_in,
                              void* d_out, int out_size, void* d_ws, size_t ws_size,
                              hipStream_t stream)
{
    const int S = 120, T = 10, B = 128, E = 80, HW = 75, HS = 700, V = 30000;
    const int Nw = S * B;            // 15360
    const int Gw = 3 * HW;           // 225
    const int Gs = 3 * HS;           // 2100
    (void)in_sizes; (void)n_in; (void)out_size; (void)ws_size;

    const int*   x       = (const int*)d_in[0];
    const float* emb     = (const float*)d_in[1];
    const float* we_Wih0 = (const float*)d_in[2],  *we_Whh0 = (const float*)d_in[3];
    const float* we_bih0 = (const float*)d_in[4],  *we_bhh0 = (const float*)d_in[5];
    const float* we_Wih1 = (const float*)d_in[6],  *we_Whh1 = (const float*)d_in[7];
    const float* we_bih1 = (const float*)d_in[8],  *we_bhh1 = (const float*)d_in[9];
    const float* se_Wih0 = (const float*)d_in[10], *se_Whh0 = (const float*)d_in[11];
    const float* se_bih0 = (const float*)d_in[12], *se_bhh0 = (const float*)d_in[13];
    const float* se_Wih1 = (const float*)d_in[14], *se_Whh1 = (const float*)d_in[15];
    const float* se_bih1 = (const float*)d_in[16], *se_bhh1 = (const float*)d_in[17];

    // ---- arena (132.5 MB total; proven-safe < 142.2 MB) ----
    // words stride 304 -> 320 so KP%64==0 for global_load_lds (no tail).
    char* ws = (char*)d_ws;
    const size_t oP1 = 9830400;                  // words bf16 [Nw,320]
    const size_t oP2 = oP1 + 49152000;           // y0w [10,Nw,160]b | y0s [Nw,1408]b
    const size_t oP3 = oP2 + 43008000;           // embW 27MB | bufL0+bufL1 43MB
    const size_t r4  = 30516480;                 // region 4 (word wts / sent overlays)
    const size_t total = oP3 + r4 + 256;         // 132,507,136 (+zero scratch)

    // word-phase pointers
    bf16*  words  = (bf16*)ws;
    bf16*  y0w    = (bf16*)(ws + oP1);
    bf16*  embW   = (bf16*)(ws + oP2);
    float* h_w0   = (float*)(ws + oP3);
    float* h_w1   = (float*)(ws + oP3 + 9216000);
    bf16*  pingW  = (bf16*)(ws + oP3 + 18432000);        // 2 x 5,898,240 B
    bf16*  Whh0bw = (bf16*)(ws + oP3 + 30228480);        // [2,225,80]
    bf16*  Whh1bw = (bf16*)(ws + oP3 + 30300480);
    bf16*  Wih1pw = (bf16*)(ws + oP3 + 30372480);        // [2,225,160] ends at r4
    const long PWE = 2L * Nw * 96;                       // ping stride elems
    // sentence-phase overlays
    bf16*  y0s    = (bf16*)(ws + oP1);                   // [Nw,1408]
    bf16*  bufL0  = (bf16*)(ws + oP2);                   // [2,20,128,2100]
    bf16*  bufL1  = (bf16*)(ws + oP2 + 21504000);
    bf16*  Whh0b  = (bf16*)(ws + oP3);                   // [2,2100,700]
    bf16*  Whh1b  = (bf16*)(ws + oP3 + 5880000);
    bf16*  hbf0   = (bf16*)(ws + oP3 + 11760000);        // 2 pings x 358,400
    bf16*  hbf1   = (bf16*)(ws + oP3 + 12476800);
    float* h_s0   = (float*)(ws + oP3 + 13193600);
    float* h_s1   = (float*)(ws + oP3 + 13910400);
    bf16*  Wih0p  = (bf16*)(ws + oP3 + 14627200);        // [2,2176,320] = 2,785,280
    bf16*  Wih1p  = (bf16*)(ws + oP3 + 17412480);        // [2,2176,1408] = 12,255,232
    const bf16* zscr = (const bf16*)(ws + oP3 + r4);     // 256B zeros (never written)

    // Targeted memsets: embW/bufL region (43MB) is fully written before any
    // read; everything else (pads, h states, weight pad cols, zero scratch).
    hipMemsetAsync(ws, 0, oP2, stream);                  // words pads + y0w/y0s holes
    hipMemsetAsync(ws + oP3, 0, r4 + 256, stream);       // h_w*, pingW, wts, zscr

    // ===================== word encoder =====================
    // embW[d] = emb @ Wih0[d]^T : [V,80] @ [225,80]^T -> [2,V,225]
    gemm_mfma<<<dim3((Gw + MBN - 1) / MBN, (V + MBM - 1) / MBM, 2), 256, 0, stream>>>(
        emb, 0, we_Wih0, (long)Gw * E, embW, (long)V * Gw, V, Gw, E);
    // weight prep (bf16, padded)
    for (int d = 0; d < 2; ++d) {
        f2bpad<<<(225 * 80 + 255) / 256, 256, 0, stream>>>(
            we_Whh0 + (long)d * 225 * 75, Whh0bw + (long)d * 225 * 80, 225, 75, 80);
        f2bpad<<<(225 * 80 + 255) / 256, 256, 0, stream>>>(
            we_Whh1 + (long)d * 225 * 75, Whh1bw + (long)d * 225 * 80, 225, 75, 80);
        f2bremap<<<(225 * 160 + 255) / 256, 256, 0, stream>>>(
            we_Wih1 + (long)d * 225 * 150, Wih1pw + (long)d * 225 * 160, 225);
    }
    dim3 wgrid(5, Nw / 128, 2);
    // ---- layer 0 ----
    for (int k = 0; k < T; ++k) {
        int p = k & 1;
        gru_word0_fused<<<wgrid, 512, 0, stream>>>(
            x, embW, Whh0bw, we_bih0, we_bhh0,
            pingW + (long)p * PWE, pingW + (long)(p ^ 1) * PWE, h_w0, y0w, T, k);
    }
    hipMemsetAsync(pingW, 0, 11796480, stream);    // re-zero both pings for layer 1
    // ---- layer 1 ----
    for (int k = 0; k < T; ++k) {
        int p = k & 1;
        gru_word1_fused<<<wgrid, 512, 0, stream>>>(
            y0w, Wih1pw, Whh1bw, we_bih1, we_bhh1,
            pingW + (long)p * PWE, pingW + (long)(p ^ 1) * PWE, h_w1, T, k);
    }
    {
        long tot = (long)Nw * 4 * HW;
        concat4<bf16><<<(tot + 255) / 256, 256, 0, stream>>>(h_w0, h_w1, words, Nw, HW, 320);
    }

    // ===================== sentence encoder =====================
    {
        long nwh = 2LL * Gs * HS;
        f2b<<<(nwh + 255) / 256, 256, 0, stream>>>(se_Whh0, Whh0b, nwh);
        f2b<<<(nwh + 255) / 256, 256, 0, stream>>>(se_Whh1, Whh1b, nwh);
        for (int d = 0; d < 2; ++d) {
            f2bpad<<<((long)2100 * 320 + 255) / 256, 256, 0, stream>>>(
                se_Wih0 + (long)d * 2100 * 300, Wih0p + (long)d * 2176 * 320, 2100, 300, 320);
            f2bpad<<<((long)2100 * 1408 + 255) / 256, 256, 0, stream>>>(
                se_Wih1 + (long)d * 2100 * 1400, Wih1p + (long)d * 2176 * 1408, 2100, 1400, 1408);
        }
    }
    hipMemsetAsync(ws + oP3 + 11760000, 0, 2867200, stream);  // hbf0,hbf1,h_s0,h_s1

    const unsigned ldsBytes = 67584;   // 66 x 1KB
    const int C2 = 20, NC = 6;   // pipeline: slot t = l0 chunk t + l1 chunk t-1
    const int nblk = ((Gs + 127) / 128) * ((C2 * B) / 128);   // 17*20 = 340

    for (int t = 0; t <= NC; ++t) {
        if (t < NC) {               // l0 xw for chunk t (KP=320)
            int tb0 = t * C2, tb1 = S - t * C2 - C2;
            gemm_bt<<<dim3(nblk, 1, 2), 256, 0, stream>>>(
                words + (long)tb0 * B * 320, (long)(tb1 - tb0) * B * 320,
                Wih0p, (long)2176 * 320,
                bufL0, (long)C2 * B * Gs, C2 * B, Gs, 320);
        }
        if (t >= 1) {               // l1 xw for chunk t-1 (KP=1408)
            int c = t - 1, tb0 = c * C2, tb1 = S - c * C2 - C2;
            gemm_bt<<<dim3(nblk, 1, 2), 256, 0, stream>>>(
                y0s + (long)tb0 * B * 1408, (long)(tb1 - tb0) * B * 1408,
                Wih1p, (long)2176 * 1408,
                bufL1, (long)C2 * B * Gs, C2 * B, Gs, 1408);
        }
        for (int i = 0; i < C2; ++i) {
            StepJob jobs[2]; int nj = 0;
            if (t < NC) {           // layer-0 job, chunk t
                int k = t * C2 + i;
                StepJob J;
                J.Whh = Whh0b; J.xw = bufL0; J.bih = se_bih0; J.bhh = se_bhh0;
                J.h = h_s0;
                int p = k & 1;
                J.hr = hbf0 + (long)p * HBPE; J.hw = hbf0 + (long)(p ^ 1) * HBPE;
                J.y = y0s; J.zb = zscr;
                J.te0 = k; J.te1 = S - 1 - k; J.tl0 = i; J.tl1 = C2 - 1 - i;
                jobs[nj++] = J;
            }
            if (t >= 1) {           // layer-1 job, chunk t-1
                int k = (t - 1) * C2 + i;
                StepJob J;
                J.Whh = Whh1b; J.xw = bufL1; J.bih = se_bih1; J.bhh = se_bhh1;
                J.h = h_s1;
                int p = k & 1;
                J.hr = hbf1 + (long)p * HBPE; J.hw = hbf1 + (long)(p ^ 1) * HBPE;
                J.y = nullptr; J.zb = zscr;
                J.te0 = k; J.te1 = S - 1 - k; J.tl0 = i; J.tl1 = C2 - 1 - i;
                jobs[nj++] = J;
            }
            if (nj == 1) jobs[1] = jobs[0];
            gru_step_sent2<<<dim3(44, nj, 2), 512, ldsBytes, stream>>>(
                jobs[0], jobs[1], C2);
        }
    }

    // out[1, B, 4*HS] = [sf0 | sb0 | sf1 | sb1]  (float32)
    {
        long tot = (long)B * 4 * HS;
        concat4<float><<<(tot + 255) / 256, 256, 0, stream>>>(
            h_s0, h_s1, (float*)d_out, B, HS, 4 * HS);
    }
}

// Round 11
// 3099.882 us; speedup vs baseline: 1.0489x; 1.0489x over previous
//
#include <hip/hip_runtime.h>
#include <hip/hip_bf16.h>

typedef __hip_bfloat16 bf16;
typedef __attribute__((ext_vector_type(8))) short bf16x8;   // MFMA A/B frag (8 bf16)
typedef __attribute__((ext_vector_type(4))) short bf16x4;
typedef __attribute__((ext_vector_type(4))) float f32x4;    // MFMA C/D frag

__device__ __forceinline__ void stC(float* p, float v) { *p = v; }
__device__ __forceinline__ void stC(bf16* p, float v)  { *p = __float2bfloat16(v); }

__device__ __forceinline__ short f2s(float f) {
    bf16 b = __float2bfloat16(f);
    return __builtin_bit_cast(short, b);
}

// global -> LDS direct copy, 16B per lane (lds dest = wave-uniform base + lane*16)
__device__ __forceinline__ void gload16(const void* gp, void* lp) {
    __builtin_amdgcn_global_load_lds(
        (const __attribute__((address_space(1))) void*)gp,
        (__attribute__((address_space(3))) void*)lp, 16, 0, 0);
}

// NaN-proof activations (clamp = no-op on sane data, sanitizes garbage).
__device__ __forceinline__ float sigm(float x) {
    x = fminf(fmaxf(x, -40.f), 40.f);
    return 1.f / (1.f + expf(-x));
}
__device__ __forceinline__ float tanh_s(float x) {
    x = fminf(fmaxf(x, -20.f), 20.f);
    float e = expf(2.f * x);
    return 1.f - 2.f / (e + 1.f);
}

// 16B-aligned 8-element loads -> bf16x8
__device__ __forceinline__ bf16x8 ld8(const bf16* p) {
    return *reinterpret_cast<const bf16x8*>(p);
}
__device__ __forceinline__ bf16x8 ld8(const float* p) {
    const float4 f0 = *reinterpret_cast<const float4*>(p);
    const float4 f1 = *reinterpret_cast<const float4*>(p + 4);
    bf16x8 v;
    v[0] = f2s(f0.x); v[1] = f2s(f0.y); v[2] = f2s(f0.z); v[3] = f2s(f0.w);
    v[4] = f2s(f1.x); v[5] = f2s(f1.y); v[6] = f2s(f1.z); v[7] = f2s(f1.w);
    return v;
}
// 8B-aligned 8-element load (rows with odd*8B stride)
__device__ __forceinline__ bf16x8 ld8_8B(const bf16* p) {
    bf16x4 lo = *reinterpret_cast<const bf16x4*>(p);
    bf16x4 hi = *reinterpret_cast<const bf16x4*>(p + 4);
    bf16x8 v;
    v[0] = lo[0]; v[1] = lo[1]; v[2] = lo[2]; v[3] = lo[3];
    v[4] = hi[0]; v[5] = hi[1]; v[6] = hi[2]; v[7] = hi[3];
    return v;
}

// f32 -> bf16 bulk convert
__global__ void f2b(const float* __restrict__ src, bf16* __restrict__ dst, long n) {
    long i = (long)blockIdx.x * 256 + threadIdx.x;
    if (i < n) dst[i] = __float2bfloat16(src[i]);
}
// f32 [rows,Ks] -> bf16 [rows,Kd] with zero pad cols
__global__ void f2bpad(const float* __restrict__ src, bf16* __restrict__ dst,
                       int rows, int Ks, int Kd) {
    long i = (long)blockIdx.x * 256 + threadIdx.x;
    if (i >= (long)rows * Kd) return;
    int c = i % Kd; long r = i / Kd;
    dst[i] = __float2bfloat16(c < Ks ? src[r * Ks + c] : 0.f);
}
// word Wih1 remap: f32 [rows,150] -> bf16 [rows,160]; col c<75 -> c;
// 80<=c<155 -> c-5; else 0 (matches y0w padded layout d*80+j).
__global__ void f2bremap(const float* __restrict__ src, bf16* __restrict__ dst, int rows) {
    long i = (long)blockIdx.x * 256 + threadIdx.x;
    if (i >= (long)rows * 160) return;
    int c = i % 160; long r = i / 160;
    float v = 0.f;
    if (c < 75) v = src[r * 150 + c];
    else if (c >= 80 && c < 155) v = src[r * 150 + c - 5];
    dst[i] = __float2bfloat16(v);
}

// ==================== MFMA GEMM (f32 inputs, embW only) ====================
#define MBM 128
#define MBN 64
#define MLD 40

__global__ __launch_bounds__(256) void gemm_mfma(
    const float* __restrict__ A, long sAd,
    const float* __restrict__ W, long sWd,
    bf16* __restrict__ C, long sCd,
    int M, int Nc, int K)   // K % 8 == 0
{
    __shared__ bf16 As[MBM * MLD];
    __shared__ bf16 Ws[MBN * MLD];
    const int d = blockIdx.z;
    A += (long)d * sAd; W += (long)d * sWd; C += (long)d * sCd;
    const int m0 = blockIdx.y * MBM;
    const int n0 = blockIdx.x * MBN;
    const int tid = threadIdx.x;
    const int w = tid >> 6, l = tid & 63;
    const int lr = l & 15, lq = l >> 4;

    f32x4 acc[2][4] = {};
    for (int k0 = 0; k0 < K; k0 += 32) {
#pragma unroll
        for (int i = 0; i < 2; ++i) {
            int u = tid + i * 256;
            int r = u >> 2, kk = (u & 3) * 8;
            bf16x8 v = {};
            if (m0 + r < M && k0 + kk < K)
                v = ld8(A + (long)(m0 + r) * K + k0 + kk);
            *reinterpret_cast<bf16x8*>(&As[r * MLD + kk]) = v;
        }
        {
            int r = tid >> 2, kk = (tid & 3) * 8;
            bf16x8 v = {};
            if (n0 + r < Nc && k0 + kk < K)
                v = ld8(W + (long)(n0 + r) * K + k0 + kk);
            *reinterpret_cast<bf16x8*>(&Ws[r * MLD + kk]) = v;
        }
        __syncthreads();
        bf16x8 af[2], bw[4];
        af[0] = *reinterpret_cast<const bf16x8*>(&As[(w * 32 + lr) * MLD + lq * 8]);
        af[1] = *reinterpret_cast<const bf16x8*>(&As[(w * 32 + 16 + lr) * MLD + lq * 8]);
#pragma unroll
        for (int ni = 0; ni < 4; ++ni)
            bw[ni] = *reinterpret_cast<const bf16x8*>(&Ws[(ni * 16 + lr) * MLD + lq * 8]);
#pragma unroll
        for (int mi = 0; mi < 2; ++mi)
#pragma unroll
            for (int ni = 0; ni < 4; ++ni)
                acc[mi][ni] = __builtin_amdgcn_mfma_f32_16x16x32_bf16(
                    af[mi], bw[ni], acc[mi][ni], 0, 0, 0);
        __syncthreads();
    }
#pragma unroll
    for (int mi = 0; mi < 2; ++mi)
#pragma unroll
        for (int reg = 0; reg < 4; ++reg) {
            int m = m0 + w * 32 + mi * 16 + lq * 4 + reg;
            if (m >= M) continue;
#pragma unroll
            for (int ni = 0; ni < 4; ++ni) {
                int n = n0 + ni * 16 + lr;
                if (n < Nc) stC(&C[(long)m * Nc + n], acc[mi][ni][reg]);
            }
        }
}

// ===== all-bf16 GEMM: 128x128 tile, BK=64, XOR-swizzled LDS, prefetch =====
// (ROUND-9 PROVEN VERSION: 59 us @ KP=1408, 0 bank conflicts. Round-10's
// global_load_lds variant regressed to 67 us — the barrier drains vmcnt(0),
// killing the cross-iteration prefetch; register staging keeps the k+1
// loads in flight through the MFMA phase via compiler waitcnt.)
// C[d] = A[d] (MxKP bf16, M%128==0, KP%8==0) @ W[d]^T
// (W: [NcPad x KP] bf16, NcPad 128-aligned, pad rows/cols zero).
// LDS: linear [128][64] bf16 with granule ^= (row&7) on write AND read.
// Band-of-8 x-tile swizzle for A-panel L2 reuse.
__global__ __launch_bounds__(256) void gemm_bt(
    const bf16* __restrict__ A, long sAd,
    const bf16* __restrict__ W, long sWd,
    bf16* __restrict__ C, long sCd,
    int M, int Nc, int KP)
{
    __shared__ bf16 As[128 * 64];
    __shared__ bf16 Ws[128 * 64];
    const int d = blockIdx.z;
    A += (long)d * sAd; W += (long)d * sWd; C += (long)d * sCd;
    const int nx = (Nc + 127) >> 7, ny = M >> 7;
    int id = blockIdx.x;
    int band = id / (8 * ny);
    int rr = id - band * 8 * ny;
    int bwd = nx - band * 8; if (bwd > 8) bwd = 8;
    const int bx = band * 8 + rr % bwd;
    const int by = rr / bwd;
    const int m0 = by << 7;
    const int n0 = bx << 7;
    const int tid = threadIdx.x;
    const int w = tid >> 6, l = tid & 63;
    const int lr = l & 15, lq = l >> 4;

    const int sr = tid >> 3;            // staging row base 0..31 (+32*i)
    const int sg = tid & 7;             // staging 8-elem granule 0..7
    const bf16x8 z8 = {};
    bf16x8 ra[4], rb[4];
    auto stage = [&](int k0) {
        const bool kin = (k0 + sg * 8) < KP;     // whole granule in (KP%8==0)
#pragma unroll
        for (int i = 0; i < 4; ++i)
            ra[i] = kin ? ld8(A + (long)(m0 + sr + i * 32) * KP + k0 + sg * 8) : z8;
#pragma unroll
        for (int i = 0; i < 4; ++i)
            rb[i] = kin ? ld8(W + (long)(n0 + sr + i * 32) * KP + k0 + sg * 8) : z8;
    };

    f32x4 acc[2][8] = {};
    stage(0);
    for (int k0 = 0; k0 < KP; k0 += 64) {
#pragma unroll
        for (int i = 0; i < 4; ++i) {
            const int r = sr + i * 32;
            const int g = sg ^ (r & 7);          // XOR-granule swizzle (write)
            *reinterpret_cast<bf16x8*>(&As[r * 64 + g * 8]) = ra[i];
            *reinterpret_cast<bf16x8*>(&Ws[r * 64 + g * 8]) = rb[i];
        }
        __syncthreads();
        if (k0 + 64 < KP) stage(k0 + 64);        // prefetch overlaps MFMA
#pragma unroll
        for (int ks = 0; ks < 2; ++ks) {
            const int gb = ks * 4 + lq;          // pre-swizzle granule
            bf16x8 af[2], bw8[8];
#pragma unroll
            for (int mi = 0; mi < 2; ++mi) {
                const int r = w * 32 + mi * 16 + lr;
                af[mi] = *reinterpret_cast<const bf16x8*>(
                    &As[r * 64 + (gb ^ (r & 7)) * 8]);
            }
#pragma unroll
            for (int ni = 0; ni < 8; ++ni) {
                const int r = ni * 16 + lr;
                bw8[ni] = *reinterpret_cast<const bf16x8*>(
                    &Ws[r * 64 + (gb ^ (r & 7)) * 8]);
            }
#pragma unroll
            for (int mi = 0; mi < 2; ++mi)
#pragma unroll
                for (int ni = 0; ni < 8; ++ni)
                    acc[mi][ni] = __builtin_amdgcn_mfma_f32_16x16x32_bf16(
                        af[mi], bw8[ni], acc[mi][ni], 0, 0, 0);
        }
        __syncthreads();
    }
#pragma unroll
    for (int mi = 0; mi < 2; ++mi)
#pragma unroll
        for (int reg = 0; reg < 4; ++reg) {
            int m = m0 + w * 32 + mi * 16 + lq * 4 + reg;
#pragma unroll
            for (int ni = 0; ni < 8; ++ni) {
                int n = n0 + ni * 16 + lr;
                if (n < Nc) C[(long)m * Nc + n] = __float2bfloat16(acc[mi][ni][reg]);
            }
        }
}

// ========== fused dual-job sentence GRU step (MFMA, LDS-staged) ==========
#define NKS 22                  // ceil(700/32)
#define HBPE (2 * 128 * 700)    // h_bf ping stride in elems

struct StepJob {
    const bf16* Whh;   // [2,2100,700] bf16
    const bf16* xw;    // [2,Cbuf,128,2100] bf16 (chunk-local)
    const float* bih;  // [2,2100]
    const float* bhh;
    float* h;          // [2,128,700] f32 master
    const bf16* hr;    // read ping
    bf16* hw;          // write pong
    bf16* y;           // [L,128,1408] or nullptr
    const bf16* zb;    // 256B zero scratch (pad-row source for gload16)
    int te0, te1;      // t_eff for d=0 / d=1 (y writes)
    int tl0, tl1;      // chunk-local t (xw reads)
};

__global__ __launch_bounds__(512) void gru_step_sent2(StepJob ja, StepJob jb, int Cbuf)
{
    extern __shared__ bf16 Wlds[];  // 66 issues x 1KB = 67,584 B
    const StepJob J = blockIdx.y ? jb : ja;
    const int jt = blockIdx.x, d = blockIdx.z;
    const int tid = threadIdx.x;
    const int w = tid >> 6, l = tid & 63;
    const int lr = l & 15, lq = l >> 4;
    const int j0c = jt * 16;
    const int jcol = j0c + lr;
    const bool jok = jcol < 700;

    // ---- Whh -> LDS via global_load_lds (issued FIRST: deepest latency).
    // unit u = issue*64 + l; issue = kk*3 + g; row = j0c + (l&15),
    // k = kk*32 + (l>>4)*8. Pad rows (>=700) read the zero scratch; the
    // k=696 granule's 4-elem overrun multiplies A's zeroed tail -> exact 0.
    const bf16* Wd = J.Whh + (long)d * 2100 * 700;
    {
        const int row = j0c + lr;
        const int kof = lq * 8;
#pragma unroll
        for (int i = 0; i < 9; ++i) {
            const int issue = w + i * 8;        // wave-uniform
            if (issue < 66) {
                const int g = issue % 3;
                const int kk = issue / 3;
                const bf16* src = (row < 700)
                    ? Wd + (long)(g * 700 + row) * 700 + kk * 32 + kof
                    : J.zb;
                gload16(src, &Wlds[(long)issue * 512]);
            }
        }
    }

    // ---- A-frags (L2-resident h state) ----
    const int arow = w * 16 + lr;
    const bf16* Ab = J.hr + ((long)d * 128 + arow) * 700;
    bf16x8 areg[NKS];
#pragma unroll
    for (int kk = 0; kk < NKS; ++kk) {
        const int kb = kk * 32 + lq * 8;
        if (kb + 8 <= 700) {
            areg[kk] = ld8_8B(Ab + kb);
        } else {
            bf16x8 v = {};
            bf16x4 lo = *reinterpret_cast<const bf16x4*>(Ab + kb);
            v[0] = lo[0]; v[1] = lo[1]; v[2] = lo[2]; v[3] = lo[3];
            areg[kk] = v;
        }
    }

    // ---- xw gates + biases (h-independent) ----
    const int te = d ? J.te1 : J.te0;
    const int tl = d ? J.tl1 : J.tl0;
    const bf16* xbase = J.xw + ((long)d * Cbuf + tl) * 128 * 2100;
    bf16 xg[3][4];
#pragma unroll
    for (int reg = 0; reg < 4; ++reg) {
        const int m = w * 16 + lq * 4 + reg;
        const bf16* xp = xbase + (long)m * 2100 + jcol;
#pragma unroll
        for (int g = 0; g < 3; ++g) xg[g][reg] = jok ? xp[g * 700] : bf16(0.f);
    }
    const int jc = jok ? jcol : 699;
    const float bir = J.bih[d * 2100 + jc];
    const float biz = J.bih[d * 2100 + 700 + jc];
    const float bin = J.bih[d * 2100 + 1400 + jc];
    const float bhr = J.bhh[d * 2100 + jc];
    const float bhz = J.bhh[d * 2100 + 700 + jc];
    const float bhn = J.bhh[d * 2100 + 1400 + jc];

    __syncthreads();   // drains vmcnt: Wlds + areg ready

    f32x4 acc[3] = {};
#pragma unroll
    for (int kk = 0; kk < NKS; ++kk)
#pragma unroll
        for (int g = 0; g < 3; ++g) {
            bf16x8 b = *reinterpret_cast<const bf16x8*>(&Wlds[((kk * 3 + g) * 64 + l) * 8]);
            acc[g] = __builtin_amdgcn_mfma_f32_16x16x32_bf16(areg[kk], b, acc[g], 0, 0, 0);
        }

    if (jok) {
#pragma unroll
        for (int reg = 0; reg < 4; ++reg) {
            const int m = w * 16 + lq * 4 + reg;
            float r  = sigm((float)xg[0][reg] + bir + acc[0][reg] + bhr);
            float z  = sigm((float)xg[1][reg] + biz + acc[1][reg] + bhz);
            float nn = tanh_s((float)xg[2][reg] + bin + r * (acc[2][reg] + bhn));
            const long hidx = ((long)d * 128 + m) * 700 + jcol;
            const float hnew = (1.f - z) * nn + z * J.h[hidx];
            J.h[hidx] = hnew;
            J.hw[hidx] = __float2bfloat16(hnew);
            if (J.y) J.y[((long)te * 128 + m) * 1408 + (long)d * 700 + jcol] =
                         __float2bfloat16(hnew);
        }
    }
}

// ============ fused word GRU steps (same structure, H=75) ============
#define WNW 15360

// layer 0: x-gates gathered from embW[tok]; gh via MFMA (3 ksteps).
__global__ __launch_bounds__(512) void gru_word0_fused(
    const int* __restrict__ x,       // [S,T,B]
    const bf16* __restrict__ embW,   // [2,30000,225]
    const bf16* __restrict__ Whh,    // [2,225,80] zero-padded
    const float* __restrict__ bih,   // [2,225]
    const float* __restrict__ bhh,
    const bf16* __restrict__ hr,     // ping [2,Nw,96]
    bf16* __restrict__ hw,           // pong
    float* __restrict__ h,           // [2,Nw,75] f32
    bf16* __restrict__ y,            // [T,Nw,160]
    int T, int k)
{
    __shared__ bf16 Wl[3 * 3 * 64 * 8];
    const int jt = blockIdx.x, mt = blockIdx.y, d = blockIdx.z;
    const int tid = threadIdx.x;
    const int w = tid >> 6, l = tid & 63;
    const int lr = l & 15, lq = l >> 4;
    const int j0c = jt * 16, jcol = j0c + lr;
    const bool jok = jcol < 75;
    const int t_eff = d ? (T - 1 - k) : k;

    const int na = mt * 128 + w * 16 + lr;
    const bf16* Ab = hr + ((long)d * WNW + na) * 96;
    bf16x8 areg[3];
#pragma unroll
    for (int kk = 0; kk < 3; ++kk) areg[kk] = ld8(Ab + kk * 32 + lq * 8);

    float xg[3][4];
#pragma unroll
    for (int reg = 0; reg < 4; ++reg) {
        const int m = mt * 128 + w * 16 + lq * 4 + reg;
        const int s = m >> 7, b = m & 127;
        int tok = x[(s * T + t_eff) * 128 + b];
        tok = max(0, min(29999, tok));
        const bf16* ep = embW + ((long)d * 30000 + tok) * 225;
#pragma unroll
        for (int g = 0; g < 3; ++g)
            xg[g][reg] = jok ? (float)ep[g * 75 + jcol] : 0.f;
    }
    const int jc = jok ? jcol : 74;
    const float bir = bih[d*225+jc], biz = bih[d*225+75+jc], bin = bih[d*225+150+jc];
    const float bhr = bhh[d*225+jc], bhz = bhh[d*225+75+jc], bhn = bhh[d*225+150+jc];

    const bf16* Wd = Whh + (long)d * 225 * 80;
    for (int u = tid; u < 3 * 3 * 64; u += 512) {
        int lane = u & 63;
        int g = (u >> 6) % 3;
        int kk = u / 192;
        int row = j0c + (lane & 15);
        int kb = kk * 32 + (lane >> 4) * 8;
        bf16x8 v = {};
        if (row < 75 && kb < 80) v = ld8_8B(Wd + (long)(g * 75 + row) * 80 + kb);
        *reinterpret_cast<bf16x8*>(&Wl[u * 8]) = v;
    }
    __syncthreads();

    f32x4 acc[3] = {};
#pragma unroll
    for (int kk = 0; kk < 3; ++kk)
#pragma unroll
        for (int g = 0; g < 3; ++g) {
            bf16x8 b8 = *reinterpret_cast<const bf16x8*>(&Wl[((kk*3+g)*64 + l)*8]);
            acc[g] = __builtin_amdgcn_mfma_f32_16x16x32_bf16(areg[kk], b8, acc[g], 0, 0, 0);
        }

    if (jok) {
#pragma unroll
        for (int reg = 0; reg < 4; ++reg) {
            const int m = mt * 128 + w * 16 + lq * 4 + reg;
            float r  = sigm(xg[0][reg] + bir + acc[0][reg] + bhr);
            float z  = sigm(xg[1][reg] + biz + acc[1][reg] + bhz);
            float nn = tanh_s(xg[2][reg] + bin + r * (acc[2][reg] + bhn));
            const long hif = ((long)d * WNW + m) * 75 + jcol;
            const float hnew = (1.f - z) * nn + z * h[hif];
            h[hif] = hnew;
            hw[((long)d * WNW + m) * 96 + jcol] = __float2bfloat16(hnew);
            y[((long)t_eff * WNW + m) * 160 + d * 80 + jcol] = __float2bfloat16(hnew);
        }
    }
}

// layer 1: xw (y0 @ Wih^T, 5 ksteps) AND gh (3 ksteps) fused via MFMA.
__global__ __launch_bounds__(512) void gru_word1_fused(
    const bf16* __restrict__ y0,     // [T,Nw,160]
    const bf16* __restrict__ Wih,    // [2,225,160] remapped
    const bf16* __restrict__ Whh,    // [2,225,80]
    const float* __restrict__ bih,
    const float* __restrict__ bhh,
    const bf16* __restrict__ hr,
    bf16* __restrict__ hw,
    float* __restrict__ h,           // [2,Nw,75]
    int T, int k)
{
    __shared__ bf16 Wl[8 * 3 * 64 * 8];   // 5 xw + 3 hh ksteps
    const int jt = blockIdx.x, mt = blockIdx.y, d = blockIdx.z;
    const int tid = threadIdx.x;
    const int w = tid >> 6, l = tid & 63;
    const int lr = l & 15, lq = l >> 4;
    const int j0c = jt * 16, jcol = j0c + lr;
    const bool jok = jcol < 75;
    const int t_eff = d ? (T - 1 - k) : k;

    const int na = mt * 128 + w * 16 + lr;
    const bf16* A1 = y0 + ((long)t_eff * WNW + na) * 160;
    bf16x8 a1[5];
#pragma unroll
    for (int kk = 0; kk < 5; ++kk) a1[kk] = ld8(A1 + kk * 32 + lq * 8);
    const bf16* A2 = hr + ((long)d * WNW + na) * 96;
    bf16x8 a2[3];
#pragma unroll
    for (int kk = 0; kk < 3; ++kk) a2[kk] = ld8(A2 + kk * 32 + lq * 8);

    const int jc = jok ? jcol : 74;
    const float bir = bih[d*225+jc], biz = bih[d*225+75+jc], bin = bih[d*225+150+jc];
    const float bhr = bhh[d*225+jc], bhz = bhh[d*225+75+jc], bhn = bhh[d*225+150+jc];

    const bf16* Wx = Wih + (long)d * 225 * 160;
    for (int u = tid; u < 960; u += 512) {       // 5*3*64 units
        int lane = u & 63;
        int g = (u >> 6) % 3;
        int kk = u / 192;
        int row = j0c + (lane & 15);
        int kb = kk * 32 + (lane >> 4) * 8;
        bf16x8 v = {};
        if (row < 75) v = ld8(Wx + (long)(g * 75 + row) * 160 + kb);
        *reinterpret_cast<bf16x8*>(&Wl[u * 8]) = v;
    }
    const bf16* Wd = Whh + (long)d * 225 * 80;
    for (int u = tid; u < 576; u += 512) {       // 3*3*64 units
        int lane = u & 63;
        int g = (u >> 6) % 3;
        int kk = u / 192;
        int row = j0c + (lane & 15);
        int kb = kk * 32 + (lane >> 4) * 8;
        bf16x8 v = {};
        if (row < 75 && kb < 80) v = ld8_8B(Wd + (long)(g * 75 + row) * 80 + kb);
        *reinterpret_cast<bf16x8*>(&Wl[(960 + u) * 8]) = v;
    }
    __syncthreads();

    f32x4 ax[3] = {}, ah[3] = {};
#pragma unroll
    for (int kk = 0; kk < 5; ++kk)
#pragma unroll
        for (int g = 0; g < 3; ++g) {
            bf16x8 b8 = *reinterpret_cast<const bf16x8*>(&Wl[((kk*3+g)*64 + l)*8]);
            ax[g] = __builtin_amdgcn_mfma_f32_16x16x32_bf16(a1[kk], b8, ax[g], 0, 0, 0);
        }
#pragma unroll
    for (int kk = 0; kk < 3; ++kk)
#pragma unroll
        for (int g = 0; g < 3; ++g) {
            bf16x8 b8 = *reinterpret_cast<const bf16x8*>(&Wl[(960 + (kk*3+g)*64 + l)*8]);
            ah[g] = __builtin_amdgcn_mfma_f32_16x16x32_bf16(a2[kk], b8, ah[g], 0, 0, 0);
        }

    if (jok) {
#pragma unroll
        for (int reg = 0; reg < 4; ++reg) {
            const int m = mt * 128 + w * 16 + lq * 4 + reg;
            float r  = sigm(ax[0][reg] + bir + ah[0][reg] + bhr);
            float z  = sigm(ax[1][reg] + biz + ah[1][reg] + bhz);
            float nn = tanh_s(ax[2][reg] + bin + r * (ah[2][reg] + bhn));
            const long hif = ((long)d * WNW + m) * 75 + jcol;
            const float hnew = (1.f - z) * nn + z * h[hif];
            h[hif] = hnew;
            hw[((long)d * WNW + m) * 96 + jcol] = __float2bfloat16(hnew);
        }
    }
}

// out[n*OS + c] = [ha_d0 | ha_d1 | hb_d0 | hb_d1], c in [0,4H)
template <typename OT>
__global__ void concat4(const float* __restrict__ ha, const float* __restrict__ hb,
                        OT* __restrict__ out, int N, int H, int OS)
{
    long idx = (long)blockIdx.x * 256 + threadIdx.x;
    int C4 = 4 * H;
    if (idx >= (long)N * C4) return;
    int c = idx % C4;
    long n = idx / C4;
    int blk = c / H, j = c % H;
    const float* src = (blk < 2) ? ha : hb;
    int dd = blk & 1;
    stC(&out[n * (long)OS + c], src[((long)dd * N + n) * H + j]);
}

extern "C" void kernel_launch(void* const* d_in, const int* in_sizes, int n_in,
                              void* d_out, int out_size, void* d_ws, size_t ws_size,
                              hipStream_t stream)
{
    const int S = 120, T = 10, B = 128, E = 80, HW = 75, HS = 700, V = 30000;
    const int Nw = S * B;            // 15360
    const int Gw = 3 * HW;           // 225
    const int Gs = 3 * HS;           // 2100
    (void)in_sizes; (void)n_in; (void)out_size; (void)ws_size;

    const int*   x       = (const int*)d_in[0];
    const float* emb     = (const float*)d_in[1];
    const float* we_Wih0 = (const float*)d_in[2],  *we_Whh0 = (const float*)d_in[3];
    const float* we_bih0 = (const float*)d_in[4],  *we_bhh0 = (const float*)d_in[5];
    const float* we_Wih1 = (const float*)d_in[6],  *we_Whh1 = (const float*)d_in[7];
    const float* we_bih1 = (const float*)d_in[8],  *we_bhh1 = (const float*)d_in[9];
    const float* se_Wih0 = (const float*)d_in[10], *se_Whh0 = (const float*)d_in[11];
    const float* se_bih0 = (const float*)d_in[12], *se_bhh0 = (const float*)d_in[13];
    const float* se_Wih1 = (const float*)d_in[14], *se_Whh1 = (const float*)d_in[15];
    const float* se_bih1 = (const float*)d_in[16], *se_bhh1 = (const float*)d_in[17];

    // ---- arena (132.5 MB total; proven-safe < 142.2 MB) ----
    char* ws = (char*)d_ws;
    const size_t oP1 = 9830400;                  // words bf16 [Nw,320]
    const size_t oP2 = oP1 + 49152000;           // y0w [10,Nw,160]b | y0s [Nw,1408]b
    const size_t oP3 = oP2 + 43008000;           // embW 27MB | bufL0+bufL1 43MB
    const size_t r4  = 30516480;                 // region 4 (word wts / sent overlays)
    const size_t total = oP3 + r4 + 256;         // 132,507,136 (+zero scratch)

    // word-phase pointers
    bf16*  words  = (bf16*)ws;
    bf16*  y0w    = (bf16*)(ws + oP1);
    bf16*  embW   = (bf16*)(ws + oP2);
    float* h_w0   = (float*)(ws + oP3);
    float* h_w1   = (float*)(ws + oP3 + 9216000);
    bf16*  pingW  = (bf16*)(ws + oP3 + 18432000);        // 2 x 5,898,240 B
    bf16*  Whh0bw = (bf16*)(ws + oP3 + 30228480);        // [2,225,80]
    bf16*  Whh1bw = (bf16*)(ws + oP3 + 30300480);
    bf16*  Wih1pw = (bf16*)(ws + oP3 + 30372480);        // [2,225,160] ends at r4
    const long PWE = 2L * Nw * 96;                       // ping stride elems
    // sentence-phase overlays
    bf16*  y0s    = (bf16*)(ws + oP1);                   // [Nw,1408]
    bf16*  bufL0  = (bf16*)(ws + oP2);                   // [2,20,128,2100]
    bf16*  bufL1  = (bf16*)(ws + oP2 + 21504000);
    bf16*  Whh0b  = (bf16*)(ws + oP3);                   // [2,2100,700]
    bf16*  Whh1b  = (bf16*)(ws + oP3 + 5880000);
    bf16*  hbf0   = (bf16*)(ws + oP3 + 11760000);        // 2 pings x 358,400
    bf16*  hbf1   = (bf16*)(ws + oP3 + 12476800);
    float* h_s0   = (float*)(ws + oP3 + 13193600);
    float* h_s1   = (float*)(ws + oP3 + 13910400);
    bf16*  Wih0p  = (bf16*)(ws + oP3 + 14627200);        // [2,2176,320] = 2,785,280
    bf16*  Wih1p  = (bf16*)(ws + oP3 + 17412480);        // [2,2176,1408] = 12,255,232
    const bf16* zscr = (const bf16*)(ws + oP3 + r4);     // 256B zeros (never written)

    // Targeted memsets: embW/bufL region (43MB) is fully written before any
    // read; everything else (pads, h states, weight pad cols, zero scratch).
    hipMemsetAsync(ws, 0, oP2, stream);                  // words pads + y0w/y0s holes
    hipMemsetAsync(ws + oP3, 0, r4 + 256, stream);       // h_w*, pingW, wts, zscr

    // ===================== word encoder =====================
    // embW[d] = emb @ Wih0[d]^T : [V,80] @ [225,80]^T -> [2,V,225]
    gemm_mfma<<<dim3((Gw + MBN - 1) / MBN, (V + MBM - 1) / MBM, 2), 256, 0, stream>>>(
        emb, 0, we_Wih0, (long)Gw * E, embW, (long)V * Gw, V, Gw, E);
    // weight prep (bf16, padded)
    for (int d = 0; d < 2; ++d) {
        f2bpad<<<(225 * 80 + 255) / 256, 256, 0, stream>>>(
            we_Whh0 + (long)d * 225 * 75, Whh0bw + (long)d * 225 * 80, 225, 75, 80);
        f2bpad<<<(225 * 80 + 255) / 256, 256, 0, stream>>>(
            we_Whh1 + (long)d * 225 * 75, Whh1bw + (long)d * 225 * 80, 225, 75, 80);
        f2bremap<<<(225 * 160 + 255) / 256, 256, 0, stream>>>(
            we_Wih1 + (long)d * 225 * 150, Wih1pw + (long)d * 225 * 160, 225);
    }
    dim3 wgrid(5, Nw / 128, 2);
    // ---- layer 0 ----
    for (int k = 0; k < T; ++k) {
        int p = k & 1;
        gru_word0_fused<<<wgrid, 512, 0, stream>>>(
            x, embW, Whh0bw, we_bih0, we_bhh0,
            pingW + (long)p * PWE, pingW + (long)(p ^ 1) * PWE, h_w0, y0w, T, k);
    }
    hipMemsetAsync(pingW, 0, 11796480, stream);    // re-zero both pings for layer 1
    // ---- layer 1 ----
    for (int k = 0; k < T; ++k) {
        int p = k & 1;
        gru_word1_fused<<<wgrid, 512, 0, stream>>>(
            y0w, Wih1pw, Whh1bw, we_bih1, we_bhh1,
            pingW + (long)p * PWE, pingW + (long)(p ^ 1) * PWE, h_w1, T, k);
    }
    {
        long tot = (long)Nw * 4 * HW;
        concat4<bf16><<<(tot + 255) / 256, 256, 0, stream>>>(h_w0, h_w1, words, Nw, HW, 320);
    }

    // ===================== sentence encoder =====================
    {
        long nwh = 2LL * Gs * HS;
        f2b<<<(nwh + 255) / 256, 256, 0, stream>>>(se_Whh0, Whh0b, nwh);
        f2b<<<(nwh + 255) / 256, 256, 0, stream>>>(se_Whh1, Whh1b, nwh);
        for (int d = 0; d < 2; ++d) {
            f2bpad<<<((long)2100 * 320 + 255) / 256, 256, 0, stream>>>(
                se_Wih0 + (long)d * 2100 * 300, Wih0p + (long)d * 2176 * 320, 2100, 300, 320);
            f2bpad<<<((long)2100 * 1408 + 255) / 256, 256, 0, stream>>>(
                se_Wih1 + (long)d * 2100 * 1400, Wih1p + (long)d * 2176 * 1408, 2100, 1400, 1408);
        }
    }
    hipMemsetAsync(ws + oP3 + 11760000, 0, 2867200, stream);  // hbf0,hbf1,h_s0,h_s1

    const unsigned ldsBytes = 67584;   // 66 x 1KB
    const int C2 = 20, NC = 6;   // pipeline: slot t = l0 chunk t + l1 chunk t-1
    const int nblk = ((Gs + 127) / 128) * ((C2 * B) / 128);   // 17*20 = 340

    for (int t = 0; t <= NC; ++t) {
        if (t < NC) {               // l0 xw for chunk t (KP=320)
            int tb0 = t * C2, tb1 = S - t * C2 - C2;
            gemm_bt<<<dim3(nblk, 1, 2), 256, 0, stream>>>(
                words + (long)tb0 * B * 320, (long)(tb1 - tb0) * B * 320,
                Wih0p, (long)2176 * 320,
                bufL0, (long)C2 * B * Gs, C2 * B, Gs, 320);
        }
        if (t >= 1) {               // l1 xw for chunk t-1 (KP=1408)
            int c = t - 1, tb0 = c * C2, tb1 = S - c * C2 - C2;
            gemm_bt<<<dim3(nblk, 1, 2), 256, 0, stream>>>(
                y0s + (long)tb0 * B * 1408, (long)(tb1 - tb0) * B * 1408,
                Wih1p, (long)2176 * 1408,
                bufL1, (long)C2 * B * Gs, C2 * B, Gs, 1408);
        }
        for (int i = 0; i < C2; ++i) {
            StepJob jobs[2]; int nj = 0;
            if (t < NC) {           // layer-0 job, chunk t
                int k = t * C2 + i;
                StepJob J;
                J.Whh = Whh0b; J.xw = bufL0; J.bih = se_bih0; J.bhh = se_bhh0;
                J.h = h_s0;
                int p = k & 1;
                J.hr = hbf0 + (long)p * HBPE; J.hw = hbf0 + (long)(p ^ 1) * HBPE;
                J.y = y0s; J.zb = zscr;
                J.te0 = k; J.te1 = S - 1 - k; J.tl0 = i; J.tl1 = C2 - 1 - i;
                jobs[nj++] = J;
            }
            if (t >= 1) {           // layer-1 job, chunk t-1
                int k = (t - 1) * C2 + i;
                StepJob J;
                J.Whh = Whh1b; J.xw = bufL1; J.bih = se_bih1; J.bhh = se_bhh1;
                J.h = h_s1;
                int p = k & 1;
                J.hr = hbf1 + (long)p * HBPE; J.hw = hbf1 + (long)(p ^ 1) * HBPE;
                J.y = nullptr; J.zb = zscr;
                J.te0 = k; J.te1 = S - 1 - k; J.tl0 = i; J.tl1 = C2 - 1 - i;
                jobs[nj++] = J;
            }
            if (nj == 1) jobs[1] = jobs[0];
            gru_step_sent2<<<dim3(44, nj, 2), 512, ldsBytes, stream>>>(
                jobs[0], jobs[1], C2);
        }
    }

    // out[1, B, 4*HS] = [sf0 | sb0 | sf1 | sb1]  (float32)
    {
        long tot = (long)B * 4 * HS;
        concat4<float><<<(tot + 255) / 256, 256, 0, stream>>>(
            h_s0, h_s1, (float*)d_out, B, HS, 4 * HS);
    }
}

// Round 13
// 2936.163 us; speedup vs baseline: 1.1074x; 1.0558x over previous
//
#include <hip/hip_runtime.h>
#include <hip/hip_bf16.h>

typedef __hip_bfloat16 bf16;
typedef __attribute__((ext_vector_type(8))) short bf16x8;   // MFMA A/B frag (8 bf16)
typedef __attribute__((ext_vector_type(4))) short bf16x4;
typedef __attribute__((ext_vector_type(4))) float f32x4;    // MFMA C/D frag

__device__ __forceinline__ void stC(float* p, float v) { *p = v; }
__device__ __forceinline__ void stC(bf16* p, float v)  { *p = __float2bfloat16(v); }

__device__ __forceinline__ short f2s(float f) {
    bf16 b = __float2bfloat16(f);
    return __builtin_bit_cast(short, b);
}

// global -> LDS direct copy, 16B per lane (lds dest = wave-uniform base + lane*16)
__device__ __forceinline__ void gload16(const void* gp, void* lp) {
    __builtin_amdgcn_global_load_lds(
        (const __attribute__((address_space(1))) void*)gp,
        (__attribute__((address_space(3))) void*)lp, 16, 0, 0);
}

// NaN-proof activations (clamp = no-op on sane data, sanitizes garbage).
__device__ __forceinline__ float sigm(float x) {
    x = fminf(fmaxf(x, -40.f), 40.f);
    return 1.f / (1.f + expf(-x));
}
__device__ __forceinline__ float tanh_s(float x) {
    x = fminf(fmaxf(x, -20.f), 20.f);
    float e = expf(2.f * x);
    return 1.f - 2.f / (e + 1.f);
}

// 16B-aligned 8-element loads -> bf16x8
__device__ __forceinline__ bf16x8 ld8(const bf16* p) {
    return *reinterpret_cast<const bf16x8*>(p);
}
__device__ __forceinline__ bf16x8 ld8(const float* p) {
    const float4 f0 = *reinterpret_cast<const float4*>(p);
    const float4 f1 = *reinterpret_cast<const float4*>(p + 4);
    bf16x8 v;
    v[0] = f2s(f0.x); v[1] = f2s(f0.y); v[2] = f2s(f0.z); v[3] = f2s(f0.w);
    v[4] = f2s(f1.x); v[5] = f2s(f1.y); v[6] = f2s(f1.z); v[7] = f2s(f1.w);
    return v;
}
// 8B-aligned 8-element load (rows with odd*8B stride)
__device__ __forceinline__ bf16x8 ld8_8B(const bf16* p) {
    bf16x4 lo = *reinterpret_cast<const bf16x4*>(p);
    bf16x4 hi = *reinterpret_cast<const bf16x4*>(p + 4);
    bf16x8 v;
    v[0] = lo[0]; v[1] = lo[1]; v[2] = lo[2]; v[3] = lo[3];
    v[4] = hi[0]; v[5] = hi[1]; v[6] = hi[2]; v[7] = hi[3];
    return v;
}

// f32 -> bf16 bulk convert
__global__ void f2b(const float* __restrict__ src, bf16* __restrict__ dst, long n) {
    long i = (long)blockIdx.x * 256 + threadIdx.x;
    if (i < n) dst[i] = __float2bfloat16(src[i]);
}
// f32 [rows,Ks] -> bf16 [rows,Kd] with zero pad cols
__global__ void f2bpad(const float* __restrict__ src, bf16* __restrict__ dst,
                       int rows, int Ks, int Kd) {
    long i = (long)blockIdx.x * 256 + threadIdx.x;
    if (i >= (long)rows * Kd) return;
    int c = i % Kd; long r = i / Kd;
    dst[i] = __float2bfloat16(c < Ks ? src[r * Ks + c] : 0.f);
}
// word Wih1 remap: f32 [rows,150] -> bf16 [rows,160]; col c<75 -> c;
// 80<=c<155 -> c-5; else 0 (matches y0w padded layout d*80+j).
__global__ void f2bremap(const float* __restrict__ src, bf16* __restrict__ dst, int rows) {
    long i = (long)blockIdx.x * 256 + threadIdx.x;
    if (i >= (long)rows * 160) return;
    int c = i % 160; long r = i / 160;
    float v = 0.f;
    if (c < 75) v = src[r * 150 + c];
    else if (c >= 80 && c < 155) v = src[r * 150 + c - 5];
    dst[i] = __float2bfloat16(v);
}

// ==================== MFMA GEMM (f32 inputs, embW only) ====================
#define MBM 128
#define MBN 64
#define MLD 40

__global__ __launch_bounds__(256) void gemm_mfma(
    const float* __restrict__ A, long sAd,
    const float* __restrict__ W, long sWd,
    bf16* __restrict__ C, long sCd,
    int M, int Nc, int K)   // K % 8 == 0
{
    __shared__ bf16 As[MBM * MLD];
    __shared__ bf16 Ws[MBN * MLD];
    const int d = blockIdx.z;
    A += (long)d * sAd; W += (long)d * sWd; C += (long)d * sCd;
    const int m0 = blockIdx.y * MBM;
    const int n0 = blockIdx.x * MBN;
    const int tid = threadIdx.x;
    const int w = tid >> 6, l = tid & 63;
    const int lr = l & 15, lq = l >> 4;

    f32x4 acc[2][4] = {};
    for (int k0 = 0; k0 < K; k0 += 32) {
#pragma unroll
        for (int i = 0; i < 2; ++i) {
            int u = tid + i * 256;
            int r = u >> 2, kk = (u & 3) * 8;
            bf16x8 v = {};
            if (m0 + r < M && k0 + kk < K)
                v = ld8(A + (long)(m0 + r) * K + k0 + kk);
            *reinterpret_cast<bf16x8*>(&As[r * MLD + kk]) = v;
        }
        {
            int r = tid >> 2, kk = (tid & 3) * 8;
            bf16x8 v = {};
            if (n0 + r < Nc && k0 + kk < K)
                v = ld8(W + (long)(n0 + r) * K + k0 + kk);
            *reinterpret_cast<bf16x8*>(&Ws[r * MLD + kk]) = v;
        }
        __syncthreads();
        bf16x8 af[2], bw[4];
        af[0] = *reinterpret_cast<const bf16x8*>(&As[(w * 32 + lr) * MLD + lq * 8]);
        af[1] = *reinterpret_cast<const bf16x8*>(&As[(w * 32 + 16 + lr) * MLD + lq * 8]);
#pragma unroll
        for (int ni = 0; ni < 4; ++ni)
            bw[ni] = *reinterpret_cast<const bf16x8*>(&Ws[(ni * 16 + lr) * MLD + lq * 8]);
#pragma unroll
        for (int mi = 0; mi < 2; ++mi)
#pragma unroll
            for (int ni = 0; ni < 4; ++ni)
                acc[mi][ni] = __builtin_amdgcn_mfma_f32_16x16x32_bf16(
                    af[mi], bw[ni], acc[mi][ni], 0, 0, 0);
        __syncthreads();
    }
#pragma unroll
    for (int mi = 0; mi < 2; ++mi)
#pragma unroll
        for (int reg = 0; reg < 4; ++reg) {
            int m = m0 + w * 32 + mi * 16 + lq * 4 + reg;
            if (m >= M) continue;
#pragma unroll
            for (int ni = 0; ni < 4; ++ni) {
                int n = n0 + ni * 16 + lr;
                if (n < Nc) stC(&C[(long)m * Nc + n], acc[mi][ni][reg]);
            }
        }
}

// ===== all-bf16 GEMM: 128x128 tile, BK=64, XOR-swizzled LDS, prefetch =====
// (PROVEN: 48 us @ KP=1408, 0 bank conflicts, ~654 TF — MFMA-busy time equals
// ideal compute time; structurally near its floor at this size.)
// C[d] = A[d] (MxKP bf16, M%128==0, KP%8==0) @ W[d]^T
// (W: [NcPad x KP] bf16, NcPad 128-aligned, pad rows/cols zero).
// LDS: linear [128][64] bf16 with granule ^= (row&7) on write AND read.
// Band-of-8 x-tile swizzle for A-panel L2 reuse.
__global__ __launch_bounds__(256) void gemm_bt(
    const bf16* __restrict__ A, long sAd,
    const bf16* __restrict__ W, long sWd,
    bf16* __restrict__ C, long sCd,
    int M, int Nc, int KP)
{
    __shared__ bf16 As[128 * 64];
    __shared__ bf16 Ws[128 * 64];
    const int d = blockIdx.z;
    A += (long)d * sAd; W += (long)d * sWd; C += (long)d * sCd;
    const int nx = (Nc + 127) >> 7, ny = M >> 7;
    int id = blockIdx.x;
    int band = id / (8 * ny);
    int rr = id - band * 8 * ny;
    int bwd = nx - band * 8; if (bwd > 8) bwd = 8;
    const int bx = band * 8 + rr % bwd;
    const int by = rr / bwd;
    const int m0 = by << 7;
    const int n0 = bx << 7;
    const int tid = threadIdx.x;
    const int w = tid >> 6, l = tid & 63;
    const int lr = l & 15, lq = l >> 4;

    const int sr = tid >> 3;            // staging row base 0..31 (+32*i)
    const int sg = tid & 7;             // staging 8-elem granule 0..7
    const bf16x8 z8 = {};
    bf16x8 ra[4], rb[4];
    auto stage = [&](int k0) {
        const bool kin = (k0 + sg * 8) < KP;     // whole granule in (KP%8==0)
#pragma unroll
        for (int i = 0; i < 4; ++i)
            ra[i] = kin ? ld8(A + (long)(m0 + sr + i * 32) * KP + k0 + sg * 8) : z8;
#pragma unroll
        for (int i = 0; i < 4; ++i)
            rb[i] = kin ? ld8(W + (long)(n0 + sr + i * 32) * KP + k0 + sg * 8) : z8;
    };

    f32x4 acc[2][8] = {};
    stage(0);
    for (int k0 = 0; k0 < KP; k0 += 64) {
#pragma unroll
        for (int i = 0; i < 4; ++i) {
            const int r = sr + i * 32;
            const int g = sg ^ (r & 7);          // XOR-granule swizzle (write)
            *reinterpret_cast<bf16x8*>(&As[r * 64 + g * 8]) = ra[i];
            *reinterpret_cast<bf16x8*>(&Ws[r * 64 + g * 8]) = rb[i];
        }
        __syncthreads();
        if (k0 + 64 < KP) stage(k0 + 64);        // prefetch overlaps MFMA
#pragma unroll
        for (int ks = 0; ks < 2; ++ks) {
            const int gb = ks * 4 + lq;          // pre-swizzle granule
            bf16x8 af[2], bw8[8];
#pragma unroll
            for (int mi = 0; mi < 2; ++mi) {
                const int r = w * 32 + mi * 16 + lr;
                af[mi] = *reinterpret_cast<const bf16x8*>(
                    &As[r * 64 + (gb ^ (r & 7)) * 8]);
            }
#pragma unroll
            for (int ni = 0; ni < 8; ++ni) {
                const int r = ni * 16 + lr;
                bw8[ni] = *reinterpret_cast<const bf16x8*>(
                    &Ws[r * 64 + (gb ^ (r & 7)) * 8]);
            }
#pragma unroll
            for (int mi = 0; mi < 2; ++mi)
#pragma unroll
                for (int ni = 0; ni < 8; ++ni)
                    acc[mi][ni] = __builtin_amdgcn_mfma_f32_16x16x32_bf16(
                        af[mi], bw8[ni], acc[mi][ni], 0, 0, 0);
        }
        __syncthreads();
    }
#pragma unroll
    for (int mi = 0; mi < 2; ++mi)
#pragma unroll
        for (int reg = 0; reg < 4; ++reg) {
            int m = m0 + w * 32 + mi * 16 + lq * 4 + reg;
#pragma unroll
            for (int ni = 0; ni < 8; ++ni) {
                int n = n0 + ni * 16 + lr;
                if (n < Nc) C[(long)m * Nc + n] = __float2bfloat16(acc[mi][ni][reg]);
            }
        }
}

// ========== fused dual-job sentence GRU step (MFMA, LDS-staged) ==========
#define NKS 22                  // ceil(700/32)
#define HBPE (2 * 128 * 700)    // h_bf ping stride in elems

struct StepJob {
    const bf16* Whh;   // [2,2100,700] bf16
    const bf16* xw;    // [2,Cbuf,128,2100] bf16 (chunk-local)
    const float* bih;  // [2,2100]
    const float* bhh;
    float* h;          // [2,128,700] f32 master
    const bf16* hr;    // read ping
    bf16* hw;          // write pong
    bf16* y;           // [L,128,1408] or nullptr
    const bf16* zb;    // 256B zero scratch (pad-row source for gload16)
    int te0, te1;      // t_eff for d=0 / d=1 (y writes)
    int tl0, tl1;      // chunk-local t (xw reads)
};

__global__ __launch_bounds__(512) void gru_step_sent2(StepJob ja, StepJob jb, int Cbuf)
{
    extern __shared__ bf16 Wlds[];  // 66 issues x 1KB = 67,584 B
    const StepJob J = blockIdx.y ? jb : ja;
    const int jt = blockIdx.x, d = blockIdx.z;
    const int tid = threadIdx.x;
    const int w = tid >> 6, l = tid & 63;
    const int lr = l & 15, lq = l >> 4;
    const int j0c = jt * 16;
    const int jcol = j0c + lr;
    const bool jok = jcol < 700;

    // ---- Whh -> LDS via global_load_lds (issued FIRST: deepest latency) ----
    const bf16* Wd = J.Whh + (long)d * 2100 * 700;
    {
        const int row = j0c + lr;
        const int kof = lq * 8;
#pragma unroll
        for (int i = 0; i < 9; ++i) {
            const int issue = w + i * 8;        // wave-uniform
            if (issue < 66) {
                const int g = issue % 3;
                const int kk = issue / 3;
                const bf16* src = (row < 700)
                    ? Wd + (long)(g * 700 + row) * 700 + kk * 32 + kof
                    : J.zb;
                gload16(src, &Wlds[(long)issue * 512]);
            }
        }
    }

    // ---- A-frags (L2-resident h state) ----
    const int arow = w * 16 + lr;
    const bf16* Ab = J.hr + ((long)d * 128 + arow) * 700;
    bf16x8 areg[NKS];
#pragma unroll
    for (int kk = 0; kk < NKS; ++kk) {
        const int kb = kk * 32 + lq * 8;
        if (kb + 8 <= 700) {
            areg[kk] = ld8_8B(Ab + kb);
        } else {
            bf16x8 v = {};
            bf16x4 lo = *reinterpret_cast<const bf16x4*>(Ab + kb);
            v[0] = lo[0]; v[1] = lo[1]; v[2] = lo[2]; v[3] = lo[3];
            areg[kk] = v;
        }
    }

    // ---- xw gates + biases (h-independent) ----
    const int te = d ? J.te1 : J.te0;
    const int tl = d ? J.tl1 : J.tl0;
    const bf16* xbase = J.xw + ((long)d * Cbuf + tl) * 128 * 2100;
    bf16 xg[3][4];
#pragma unroll
    for (int reg = 0; reg < 4; ++reg) {
        const int m = w * 16 + lq * 4 + reg;
        const bf16* xp = xbase + (long)m * 2100 + jcol;
#pragma unroll
        for (int g = 0; g < 3; ++g) xg[g][reg] = jok ? xp[g * 700] : bf16(0.f);
    }
    const int jc = jok ? jcol : 699;
    const float bir = J.bih[d * 2100 + jc];
    const float biz = J.bih[d * 2100 + 700 + jc];
    const float bin = J.bih[d * 2100 + 1400 + jc];
    const float bhr = J.bhh[d * 2100 + jc];
    const float bhz = J.bhh[d * 2100 + 700 + jc];
    const float bhn = J.bhh[d * 2100 + 1400 + jc];

    __syncthreads();   // drains vmcnt: Wlds + areg ready

    f32x4 acc[3] = {};
#pragma unroll
    for (int kk = 0; kk < NKS; ++kk)
#pragma unroll
        for (int g = 0; g < 3; ++g) {
            bf16x8 b = *reinterpret_cast<const bf16x8*>(&Wlds[((kk * 3 + g) * 64 + l) * 8]);
            acc[g] = __builtin_amdgcn_mfma_f32_16x16x32_bf16(areg[kk], b, acc[g], 0, 0, 0);
        }

    if (jok) {
#pragma unroll
        for (int reg = 0; reg < 4; ++reg) {
            const int m = w * 16 + lq * 4 + reg;
            float r  = sigm((float)xg[0][reg] + bir + acc[0][reg] + bhr);
            float z  = sigm((float)xg[1][reg] + biz + acc[1][reg] + bhz);
            float nn = tanh_s((float)xg[2][reg] + bin + r * (acc[2][reg] + bhn));
            const long hidx = ((long)d * 128 + m) * 700 + jcol;
            const float hnew = (1.f - z) * nn + z * J.h[hidx];
            J.h[hidx] = hnew;
            J.hw[hidx] = __float2bfloat16(hnew);
            if (J.y) J.y[((long)te * 128 + m) * 1408 + (long)d * 700 + jcol] =
                         __float2bfloat16(hnew);
        }
    }
}

// ============ fused word GRU steps (grid = (120 m-tiles, 2 dirs)) ============
// One block covers ALL 5 j-tiles (75 cols): full d-slice of weights staged
// to LDS once, A-frags/tokens loaded ONCE (the old (5,120,2) grid reloaded
// them 5x: ~24 MB/step of redundant h/y0w reads).
#define WNW 15360

// layer 0: x-gates gathered from embW[tok]; gh via MFMA (3 ksteps x 5 jt).
__global__ __launch_bounds__(512) void gru_word0_fused(
    const int* __restrict__ x,       // [S,T,B]
    const bf16* __restrict__ embW,   // [2,30000,225]
    const bf16* __restrict__ Whh,    // [2,225,80] zero-padded
    const float* __restrict__ bih,   // [2,225]
    const float* __restrict__ bhh,
    const bf16* __restrict__ hr,     // ping [2,Nw,96]
    bf16* __restrict__ hw,           // pong
    float* __restrict__ h,           // [2,Nw,75] f32
    bf16* __restrict__ y,            // [T,Nw,160]
    int T, int k)
{
    __shared__ bf16 Wl[45 * 64 * 8];   // 46,080 B: unit = jt*9 + kk*3 + g
    const int mt = blockIdx.x, d = blockIdx.y;
    const int tid = threadIdx.x;
    const int w = tid >> 6, l = tid & 63;
    const int lr = l & 15, lq = l >> 4;
    const int t_eff = d ? (T - 1 - k) : k;

    // A-frags (load once; reused across all j-tiles)
    const int na = mt * 128 + w * 16 + lr;
    const bf16* Ab = hr + ((long)d * WNW + na) * 96;
    bf16x8 areg[3];
#pragma unroll
    for (int kk = 0; kk < 3; ++kk) areg[kk] = ld8(Ab + kk * 32 + lq * 8);

    // tokens (once)
    int toks[4];
#pragma unroll
    for (int reg = 0; reg < 4; ++reg) {
        const int m = mt * 128 + w * 16 + lq * 4 + reg;
        const int s = m >> 7, b = m & 127;
        int tok = x[(s * T + t_eff) * 128 + b];
        toks[reg] = max(0, min(29999, tok));
    }

    // stage full Whh d-slice in MFMA fragment order
    const bf16* Wd = Whh + (long)d * 225 * 80;
    for (int u = tid; u < 45 * 64; u += 512) {
        int lane = u & 63;
        int c = u >> 6;                 // 0..44
        int jt = c / 9;
        int rem = c - jt * 9;
        int kk = rem / 3, g = rem - kk * 3;
        int row = jt * 16 + (lane & 15);
        int kb = kk * 32 + (lane >> 4) * 8;
        bf16x8 v = {};
        if (row < 75 && kb < 80) v = ld8_8B(Wd + (long)(g * 75 + row) * 80 + kb);
        *reinterpret_cast<bf16x8*>(&Wl[u * 8]) = v;
    }
    __syncthreads();

    const bf16* eb = embW + (long)d * 30000 * 225;
    for (int jt = 0; jt < 5; ++jt) {
        const int jcol = jt * 16 + lr;
        const bool jok = jcol < 75;
        f32x4 acc[3] = {};
#pragma unroll
        for (int kk = 0; kk < 3; ++kk)
#pragma unroll
            for (int g = 0; g < 3; ++g) {
                bf16x8 b8 = *reinterpret_cast<const bf16x8*>(
                    &Wl[((jt * 9 + kk * 3 + g) * 64 + l) * 8]);
                acc[g] = __builtin_amdgcn_mfma_f32_16x16x32_bf16(
                    areg[kk], b8, acc[g], 0, 0, 0);
            }
        if (!jok) continue;
        const float bir = bih[d*225+jcol], biz = bih[d*225+75+jcol], bin = bih[d*225+150+jcol];
        const float bhr = bhh[d*225+jcol], bhz = bhh[d*225+75+jcol], bhn = bhh[d*225+150+jcol];
#pragma unroll
        for (int reg = 0; reg < 4; ++reg) {
            const int m = mt * 128 + w * 16 + lq * 4 + reg;
            const bf16* ep = eb + (long)toks[reg] * 225;
            float xr = (float)ep[jcol];
            float xz = (float)ep[75 + jcol];
            float xn = (float)ep[150 + jcol];
            float r  = sigm(xr + bir + acc[0][reg] + bhr);
            float z  = sigm(xz + biz + acc[1][reg] + bhz);
            float nn = tanh_s(xn + bin + r * (acc[2][reg] + bhn));
            const long hif = ((long)d * WNW + m) * 75 + jcol;
            const float hnew = (1.f - z) * nn + z * h[hif];
            h[hif] = hnew;
            hw[((long)d * WNW + m) * 96 + jcol] = __float2bfloat16(hnew);
            y[((long)t_eff * WNW + m) * 160 + d * 80 + jcol] = __float2bfloat16(hnew);
        }
    }
}

// layer 1: xw (y0 @ Wih^T, 5 ksteps) AND gh (3 ksteps) fused, 5 jt looped.
__global__ __launch_bounds__(512) void gru_word1_fused(
    const bf16* __restrict__ y0,     // [T,Nw,160]
    const bf16* __restrict__ Wih,    // [2,225,160] remapped
    const bf16* __restrict__ Whh,    // [2,225,80]
    const float* __restrict__ bih,
    const float* __restrict__ bhh,
    const bf16* __restrict__ hr,
    bf16* __restrict__ hw,
    float* __restrict__ h,           // [2,Nw,75]
    int T, int k)
{
    extern __shared__ bf16 Wl1[];    // 122,880 B: xw 75 units + hh 45 units
    const int mt = blockIdx.x, d = blockIdx.y;
    const int tid = threadIdx.x;
    const int w = tid >> 6, l = tid & 63;
    const int lr = l & 15, lq = l >> 4;
    const int t_eff = d ? (T - 1 - k) : k;

    const int na = mt * 128 + w * 16 + lr;
    const bf16* A1 = y0 + ((long)t_eff * WNW + na) * 160;
    bf16x8 a1[5];
#pragma unroll
    for (int kk = 0; kk < 5; ++kk) a1[kk] = ld8(A1 + kk * 32 + lq * 8);
    const bf16* A2 = hr + ((long)d * WNW + na) * 96;
    bf16x8 a2[3];
#pragma unroll
    for (int kk = 0; kk < 3; ++kk) a2[kk] = ld8(A2 + kk * 32 + lq * 8);

    // stage Wih (xw) frags: unit = jt*15 + kk*3 + g  (75 units)
    const bf16* Wx = Wih + (long)d * 225 * 160;
    for (int u = tid; u < 75 * 64; u += 512) {
        int lane = u & 63;
        int c = u >> 6;                 // 0..74
        int jt = c / 15;
        int rem = c - jt * 15;
        int kk = rem / 3, g = rem - kk * 3;
        int row = jt * 16 + (lane & 15);
        int kb = kk * 32 + (lane >> 4) * 8;
        bf16x8 v = {};
        if (row < 75) v = ld8(Wx + (long)(g * 75 + row) * 160 + kb);
        *reinterpret_cast<bf16x8*>(&Wl1[u * 8]) = v;
    }
    // stage Whh frags at offset 75*64*8: unit = jt*9 + kk*3 + g (45 units)
    const bf16* Wd = Whh + (long)d * 225 * 80;
    for (int u = tid; u < 45 * 64; u += 512) {
        int lane = u & 63;
        int c = u >> 6;
        int jt = c / 9;
        int rem = c - jt * 9;
        int kk = rem / 3, g = rem - kk * 3;
        int row = jt * 16 + (lane & 15);
        int kb = kk * 32 + (lane >> 4) * 8;
        bf16x8 v = {};
        if (row < 75 && kb < 80) v = ld8_8B(Wd + (long)(g * 75 + row) * 80 + kb);
        *reinterpret_cast<bf16x8*>(&Wl1[(75 * 64 + u) * 8]) = v;
    }
    __syncthreads();

    for (int jt = 0; jt < 5; ++jt) {
        const int jcol = jt * 16 + lr;
        const bool jok = jcol < 75;
        f32x4 ax[3] = {}, ah[3] = {};
#pragma unroll
        for (int kk = 0; kk < 5; ++kk)
#pragma unroll
            for (int g = 0; g < 3; ++g) {
                bf16x8 b8 = *reinterpret_cast<const bf16x8*>(
                    &Wl1[((jt * 15 + kk * 3 + g) * 64 + l) * 8]);
                ax[g] = __builtin_amdgcn_mfma_f32_16x16x32_bf16(
                    a1[kk], b8, ax[g], 0, 0, 0);
            }
#pragma unroll
        for (int kk = 0; kk < 3; ++kk)
#pragma unroll
            for (int g = 0; g < 3; ++g) {
                bf16x8 b8 = *reinterpret_cast<const bf16x8*>(
                    &Wl1[(75 * 64 + (jt * 9 + kk * 3 + g) * 64 + l) * 8]);
                ah[g] = __builtin_amdgcn_mfma_f32_16x16x32_bf16(
                    a2[kk], b8, ah[g], 0, 0, 0);
            }
        if (!jok) continue;
        const float bir = bih[d*225+jcol], biz = bih[d*225+75+jcol], bin = bih[d*225+150+jcol];
        const float bhr = bhh[d*225+jcol], bhz = bhh[d*225+75+jcol], bhn = bhh[d*225+150+jcol];
#pragma unroll
        for (int reg = 0; reg < 4; ++reg) {
            const int m = mt * 128 + w * 16 + lq * 4 + reg;
            float r  = sigm(ax[0][reg] + bir + ah[0][reg] + bhr);
            float z  = sigm(ax[1][reg] + biz + ah[1][reg] + bhz);
            float nn = tanh_s(ax[2][reg] + bin + r * (ah[2][reg] + bhn));
            const long hif = ((long)d * WNW + m) * 75 + jcol;
            const float hnew = (1.f - z) * nn + z * h[hif];
            h[hif] = hnew;
            hw[((long)d * WNW + m) * 96 + jcol] = __float2bfloat16(hnew);
        }
    }
}

// out[n*OS + c] = [ha_d0 | ha_d1 | hb_d0 | hb_d1], c in [0,4H)
template <typename OT>
__global__ void concat4(const float* __restrict__ ha, const float* __restrict__ hb,
                        OT* __restrict__ out, int N, int H, int OS)
{
    long idx = (long)blockIdx.x * 256 + threadIdx.x;
    int C4 = 4 * H;
    if (idx >= (long)N * C4) return;
    int c = idx % C4;
    long n = idx / C4;
    int blk = c / H, j = c % H;
    const float* src = (blk < 2) ? ha : hb;
    int dd = blk & 1;
    stC(&out[n * (long)OS + c], src[((long)dd * N + n) * H + j]);
}

extern "C" void kernel_launch(void* const* d_in, const int* in_sizes, int n_in,
                              void* d_out, int out_size, void* d_ws, size_t ws_size,
                              hipStream_t stream)
{
    const int S = 120, T = 10, B = 128, E = 80, HW = 75, HS = 700, V = 30000;
    const int Nw = S * B;            // 15360
    const int Gw = 3 * HW;           // 225
    const int Gs = 3 * HS;           // 2100
    (void)in_sizes; (void)n_in; (void)out_size; (void)ws_size;

    const int*   x       = (const int*)d_in[0];
    const float* emb     = (const float*)d_in[1];
    const float* we_Wih0 = (const float*)d_in[2],  *we_Whh0 = (const float*)d_in[3];
    const float* we_bih0 = (const float*)d_in[4],  *we_bhh0 = (const float*)d_in[5];
    const float* we_Wih1 = (const float*)d_in[6],  *we_Whh1 = (const float*)d_in[7];
    const float* we_bih1 = (const float*)d_in[8],  *we_bhh1 = (const float*)d_in[9];
    const float* se_Wih0 = (const float*)d_in[10], *se_Whh0 = (const float*)d_in[11];
    const float* se_bih0 = (const float*)d_in[12], *se_bhh0 = (const float*)d_in[13];
    const float* se_Wih1 = (const float*)d_in[14], *se_Whh1 = (const float*)d_in[15];
    const float* se_bih1 = (const float*)d_in[16], *se_bhh1 = (const float*)d_in[17];

    // ---- arena (132.5 MB total; proven-safe < 142.2 MB) ----
    char* ws = (char*)d_ws;
    const size_t oP1 = 9830400;                  // words bf16 [Nw,320]
    const size_t oP2 = oP1 + 49152000;           // y0w [10,Nw,160]b | y0s [Nw,1408]b
    const size_t oP3 = oP2 + 43008000;           // embW 27MB | bufL0+bufL1 43MB
    const size_t r4  = 30516480;                 // region 4 (word wts / sent overlays)
    const size_t total = oP3 + r4 + 256;         // 132,507,136 (+zero scratch)

    // word-phase pointers
    bf16*  words  = (bf16*)ws;
    bf16*  y0w    = (bf16*)(ws + oP1);
    bf16*  embW   = (bf16*)(ws + oP2);
    float* h_w0   = (float*)(ws + oP3);
    float* h_w1   = (float*)(ws + oP3 + 9216000);
    bf16*  pingW  = (bf16*)(ws + oP3 + 18432000);        // 2 x 5,898,240 B
    bf16*  Whh0bw = (bf16*)(ws + oP3 + 30228480);        // [2,225,80]
    bf16*  Whh1bw = (bf16*)(ws + oP3 + 30300480);
    bf16*  Wih1pw = (bf16*)(ws + oP3 + 30372480);        // [2,225,160] ends at r4
    const long PWE = 2L * Nw * 96;                       // ping stride elems
    // sentence-phase overlays
    bf16*  y0s    = (bf16*)(ws + oP1);                   // [Nw,1408]
    bf16*  bufL0  = (bf16*)(ws + oP2);                   // [2,20,128,2100]
    bf16*  bufL1  = (bf16*)(ws + oP2 + 21504000);
    bf16*  Whh0b  = (bf16*)(ws + oP3);                   // [2,2100,700]
    bf16*  Whh1b  = (bf16*)(ws + oP3 + 5880000);
    bf16*  hbf0   = (bf16*)(ws + oP3 + 11760000);        // 2 pings x 358,400
    bf16*  hbf1   = (bf16*)(ws + oP3 + 12476800);
    float* h_s0   = (float*)(ws + oP3 + 13193600);
    float* h_s1   = (float*)(ws + oP3 + 13910400);
    bf16*  Wih0p  = (bf16*)(ws + oP3 + 14627200);        // [2,2176,320]
    bf16*  Wih1p  = (bf16*)(ws + oP3 + 17412480);        // [2,2176,1408]
    const bf16* zscr = (const bf16*)(ws + oP3 + r4);     // 256B zeros (never written)

    // Targeted memsets: embW/bufL region (43MB) is fully written before any
    // read; everything else (pads, h states, weight pad cols, zero scratch).
    hipMemsetAsync(ws, 0, oP2, stream);                  // words pads + y0w/y0s holes
    hipMemsetAsync(ws + oP3, 0, r4 + 256, stream);       // h_w*, pingW, wts, zscr

    // ===================== word encoder =====================
    // embW[d] = emb @ Wih0[d]^T : [V,80] @ [225,80]^T -> [2,V,225]
    gemm_mfma<<<dim3((Gw + MBN - 1) / MBN, (V + MBM - 1) / MBM, 2), 256, 0, stream>>>(
        emb, 0, we_Wih0, (long)Gw * E, embW, (long)V * Gw, V, Gw, E);
    // weight prep (bf16, padded)
    for (int d = 0; d < 2; ++d) {
        f2bpad<<<(225 * 80 + 255) / 256, 256, 0, stream>>>(
            we_Whh0 + (long)d * 225 * 75, Whh0bw + (long)d * 225 * 80, 225, 75, 80);
        f2bpad<<<(225 * 80 + 255) / 256, 256, 0, stream>>>(
            we_Whh1 + (long)d * 225 * 75, Whh1bw + (long)d * 225 * 80, 225, 75, 80);
        f2bremap<<<(225 * 160 + 255) / 256, 256, 0, stream>>>(
            we_Wih1 + (long)d * 225 * 150, Wih1pw + (long)d * 225 * 160, 225);
    }
    dim3 wgrid(Nw / 128, 2);   // 120 x 2
    // ---- layer 0 ----
    for (int k = 0; k < T; ++k) {
        int p = k & 1;
        gru_word0_fused<<<wgrid, 512, 0, stream>>>(
            x, embW, Whh0bw, we_bih0, we_bhh0,
            pingW + (long)p * PWE, pingW + (long)(p ^ 1) * PWE, h_w0, y0w, T, k);
    }
    hipMemsetAsync(pingW, 0, 11796480, stream);    // re-zero both pings for layer 1
    // ---- layer 1 ----
    for (int k = 0; k < T; ++k) {
        int p = k & 1;
        gru_word1_fused<<<wgrid, 512, 122880, stream>>>(
            y0w, Wih1pw, Whh1bw, we_bih1, we_bhh1,
            pingW + (long)p * PWE, pingW + (long)(p ^ 1) * PWE, h_w1, T, k);
    }
    {
        long tot = (long)Nw * 4 * HW;
        concat4<bf16><<<(tot + 255) / 256, 256, 0, stream>>>(h_w0, h_w1, words, Nw, HW, 320);
    }

    // ===================== sentence encoder =====================
    {
        long nwh = 2LL * Gs * HS;
        f2b<<<(nwh + 255) / 256, 256, 0, stream>>>(se_Whh0, Whh0b, nwh);
        f2b<<<(nwh + 255) / 256, 256, 0, stream>>>(se_Whh1, Whh1b, nwh);
        for (int d = 0; d < 2; ++d) {
            f2bpad<<<((long)2100 * 320 + 255) / 256, 256, 0, stream>>>(
                se_Wih0 + (long)d * 2100 * 300, Wih0p + (long)d * 2176 * 320, 2100, 300, 320);
            f2bpad<<<((long)2100 * 1408 + 255) / 256, 256, 0, stream>>>(
                se_Wih1 + (long)d * 2100 * 1400, Wih1p + (long)d * 2176 * 1408, 2100, 1400, 1408);
        }
    }
    hipMemsetAsync(ws + oP3 + 11760000, 0, 2867200, stream);  // hbf0,hbf1,h_s0,h_s1

    const unsigned ldsBytes = 67584;   // 66 x 1KB
    const int C2 = 20, NC = 6;   // pipeline: slot t = l0 chunk t + l1 chunk t-1
    const int nblk = ((Gs + 127) / 128) * ((C2 * B) / 128);   // 17*20 = 340

    for (int t = 0; t <= NC; ++t) {
        if (t < NC) {               // l0 xw for chunk t (KP=320)
            int tb0 = t * C2, tb1 = S - t * C2 - C2;
            gemm_bt<<<dim3(nblk, 1, 2), 256, 0, stream>>>(
                words + (long)tb0 * B * 320, (long)(tb1 - tb0) * B * 320,
                Wih0p, (long)2176 * 320,
                bufL0, (long)C2 * B * Gs, C2 * B, Gs, 320);
        }
        if (t >= 1) {               // l1 xw for chunk t-1 (KP=1408)
            int c = t - 1, tb0 = c * C2, tb1 = S - c * C2 - C2;
            gemm_bt<<<dim3(nblk, 1, 2), 256, 0, stream>>>(
                y0s + (long)tb0 * B * 1408, (long)(tb1 - tb0) * B * 1408,
                Wih1p, (long)2176 * 1408,
                bufL1, (long)C2 * B * Gs, C2 * B, Gs, 1408);
        }
        for (int i = 0; i < C2; ++i) {
            StepJob jobs[2]; int nj = 0;
            if (t < NC) {           // layer-0 job, chunk t
                int k = t * C2 + i;
                StepJob J;
                J.Whh = Whh0b; J.xw = bufL0; J.bih = se_bih0; J.bhh = se_bhh0;
                J.h = h_s0;
                int p = k & 1;
                J.hr = hbf0 + (long)p * HBPE; J.hw = hbf0 + (long)(p ^ 1) * HBPE;
                J.y = y0s; J.zb = zscr;
                J.te0 = k; J.te1 = S - 1 - k; J.tl0 = i; J.tl1 = C2 - 1 - i;
                jobs[nj++] = J;
            }
            if (t >= 1) {           // layer-1 job, chunk t-1
                int k = (t - 1) * C2 + i;
                StepJob J;
                J.Whh = Whh1b; J.xw = bufL1; J.bih = se_bih1; J.bhh = se_bhh1;
                J.h = h_s1;
                int p = k & 1;
                J.hr = hbf1 + (long)p * HBPE; J.hw = hbf1 + (long)(p ^ 1) * HBPE;
                J.y = nullptr; J.zb = zscr;
                J.te0 = k; J.te1 = S - 1 - k; J.tl0 = i; J.tl1 = C2 - 1 - i;
                jobs[nj++] = J;
            }
            if (nj == 1) jobs[1] = jobs[0];
            gru_step_sent2<<<dim3(44, nj, 2), 512, ldsBytes, stream>>>(
                jobs[0], jobs[1], C2);
        }
    }

    // out[1, B, 4*HS] = [sf0 | sb0 | sf1 | sb1]  (float32)
    {
        long tot = (long)B * 4 * HS;
        concat4<float><<<(tot + 255) / 256, 256, 0, stream>>>(
            h_s0, h_s1, (float*)d_out, B, HS, 4 * HS);
    }
}